// Round 14
// baseline (206.325 us; speedup 1.0000x reference)
//
#include <hip/hip_runtime.h>
#include <hip/hip_bf16.h>
#include <stdint.h>

#define B_ 4
#define S_ 2048
#define H_ 1024
#define NH_ 16
#define DH_ 64
#define M_ (B_*S_)   // 8192

typedef __bf16 bf16x8 __attribute__((ext_vector_type(8)));
typedef float f32x4 __attribute__((ext_vector_type(4)));

static_assert(sizeof(__bf16) == 2, "bf16 size");

__device__ __forceinline__ uint32_t pack_bf16(float lo, float hi)
{
    union { __bf16 h[2]; uint32_t u; } t;
    t.h[0] = (__bf16)lo; t.h[1] = (__bf16)hi;
    return t.u;
}

__device__ __forceinline__ float fast_exp2(float x)
{
#if __has_builtin(__builtin_amdgcn_exp2f)
    return __builtin_amdgcn_exp2f(x);
#else
    return exp2f(x);
#endif
}

// async global->LDS, 16B per lane. LDS dest = wave-uniform base + lane*16.
__device__ __forceinline__ void gll16(void* lds, const void* g)
{
    __builtin_amdgcn_global_load_lds(
        (const __attribute__((address_space(1))) unsigned int*)g,
        (__attribute__((address_space(3))) unsigned int*)lds,
        16, 0, 0);
}

// ----------------------------------------------------------------- prep ----
__device__ __forceinline__ void cast8(const float* __restrict__ s, __bf16* __restrict__ d, int i)
{
    float4 a = *(const float4*)(s + i);
    float4 b = *(const float4*)(s + i + 4);
    bf16x8 o;
    o[0] = (__bf16)a.x; o[1] = (__bf16)a.y; o[2] = (__bf16)a.z; o[3] = (__bf16)a.w;
    o[4] = (__bf16)b.x; o[5] = (__bf16)b.y; o[6] = (__bf16)b.z; o[7] = (__bf16)b.w;
    *(bf16x8*)(d + i) = o;
}

__global__ __launch_bounds__(256)
void prep_kernel(const float* __restrict__ hs,
                 const float* __restrict__ Wq, const float* __restrict__ Wk,
                 const float* __restrict__ Wv, const float* __restrict__ Wo,
                 const float* __restrict__ mask,
                 const float* __restrict__ bq, const float* __restrict__ bk,
                 const float* __restrict__ bv,
                 __bf16* __restrict__ x_bf, __bf16* __restrict__ wqkv,
                 __bf16* __restrict__ wo_bf, float* __restrict__ msk2,
                 float* __restrict__ bqkv)
{
    const int bid = blockIdx.x, tid = threadIdx.x;
    const int nw = H_ * H_;
    if (bid < 4096) {
        cast8(hs, x_bf, bid * 2048 + tid * 8);
    } else if (bid < 4608) {
        cast8(Wq, wqkv, (bid - 4096) * 2048 + tid * 8);
    } else if (bid < 5120) {
        cast8(Wk, wqkv + nw, (bid - 4608) * 2048 + tid * 8);
    } else if (bid < 5632) {
        cast8(Wv, wqkv + 2 * nw, (bid - 5120) * 2048 + tid * 8);
    } else if (bid < 6144) {
        cast8(Wo, wo_bf, (bid - 5632) * 2048 + tid * 8);
    } else if (bid < 6148) {
        const int i = (bid - 6144) * 2048 + tid * 8;
        float4 a = *(const float4*)(mask + i);
        float4 c = *(const float4*)(mask + i + 4);
        const float L = 1.44269504089f;
        float4 sa = {a.x * L, a.y * L, a.z * L, a.w * L};
        float4 sc = {c.x * L, c.y * L, c.z * L, c.w * L};
        *(float4*)(msk2 + i)     = sa;
        *(float4*)(msk2 + i + 4) = sc;
    } else {
        const int j = (bid - 6148) * 256 + tid;
        const float* src = (j < H_) ? bq : (j < 2 * H_) ? bk : bv;
        bqkv[j] = src[j & (H_ - 1)];
    }
}

// ---------------------------------------------------------------- GEMM ----
// C[M,N] = A[M,K] @ Bw[N,K]^T + bias. bf16 in, fp32 acc.
// EPI 1: bf16 out + resid (Wo proj; LN reads bf16).
// EPI 3: fused QKV -> q bf16, k bf16, V^T via LDS-transposed coalesced write.
template<int EPI>
__global__ __launch_bounds__(256)
void gemm_bt(const __bf16* __restrict__ A, const __bf16* __restrict__ Bw,
             const float* __restrict__ bias, const float* __restrict__ resid,
             __bf16* __restrict__ outq, __bf16* __restrict__ outk,
             __bf16* __restrict__ outvt)
{
    __shared__ __align__(16) char LB[2 * 16384];
    char* As = LB;
    char* Bs = LB + 16384;

    const int tid  = threadIdx.x;
    const int lane = tid & 63, wv = tid >> 6;
    const int wr = wv >> 1, wc = wv & 1;           // 2x2 wave grid, 64x64 each
    const int m0 = blockIdx.y * 128, n0 = blockIdx.x * 128;
    const int rl = lane & 15, rg = lane >> 4;
    const int r8 = lane >> 3, sl = lane & 7;       // staging: row-in-group, slot

    f32x4 acc[4][4] = {};

    for (int k0 = 0; k0 < H_; k0 += 64) {
#pragma unroll
        for (int p = 0; p < 4; ++p) {
            const int row = p * 32 + wv * 8 + r8;
            gll16(As + (size_t)(p * 32 + wv * 8) * 128,
                  A  + (size_t)(m0 + row) * H_ + k0 + 8 * (sl ^ (row & 7)));
            gll16(Bs + (size_t)(p * 32 + wv * 8) * 128,
                  Bw + (size_t)(n0 + row) * H_ + k0 + 8 * (sl ^ (row & 7)));
        }
        __syncthreads();
#pragma unroll
        for (int ks = 0; ks < 2; ++ks) {
            const int kb = ks * 64 + rg * 16;      // byte offset in LDS row
            bf16x8 af[4], bfr[4];
#pragma unroll
            for (int m = 0; m < 4; ++m) {
                const int row = wr * 64 + m * 16 + rl;
                af[m] = *(const bf16x8*)(As + row * 128 + (kb ^ ((rl & 7) << 4)));
            }
#pragma unroll
            for (int n = 0; n < 4; ++n) {
                const int row = wc * 64 + n * 16 + rl;
                bfr[n] = *(const bf16x8*)(Bs + row * 128 + (kb ^ ((rl & 7) << 4)));
            }
#pragma unroll
            for (int m = 0; m < 4; ++m)
#pragma unroll
                for (int n = 0; n < 4; ++n)
                    acc[m][n] = __builtin_amdgcn_mfma_f32_16x16x32_bf16(af[m], bfr[n], acc[m][n], 0, 0, 0);
        }
        __syncthreads();
    }

    // epilogue: C/D layout col = lane&15, row = (lane>>4)*4 + reg   [m89]
    if (EPI == 3 && (n0 >> 10) == 2) {
        // ---- V^T: transpose the 128x128 tile in LDS (XOR-swizzled), then
        //      coalesced 16B stores (row = d, contiguous in s).
#pragma unroll
        for (int m = 0; m < 4; ++m)
#pragma unroll
            for (int n = 0; n < 4; ++n) {
                const int lcol = wc * 64 + n * 16 + rl;      // local d
                const int ls0  = wr * 64 + m * 16 + rg * 4;  // local s
                const float bv = bias[n0 + lcol];
                uint32_t w0 = pack_bf16(acc[m][n][0] + bv, acc[m][n][1] + bv);
                uint32_t w1 = pack_bf16(acc[m][n][2] + bv, acc[m][n][3] + bv);
                const int xorv = (lcol & 15) << 4;
                *(uint32_t*)(LB + lcol * 256 + ((ls0 * 2) ^ xorv))           = w0;
                *(uint32_t*)(LB + lcol * 256 + (((ls0 + 2) * 2) ^ xorv))     = w1;
            }
        __syncthreads();
        const int bb = m0 >> 11, s0g = m0 & (S_ - 1);
#pragma unroll
        for (int pass = 0; pass < 4; ++pass) {
            const int dd = pass * 32 + wv * 8 + (lane >> 3);
            const int ch = (lane & 7) * 16;                  // byte chunk in row
            const int cs = (n0 & 1023) + dd;
            const int hh = cs >> 6, dv = cs & 63;
            __bf16* dst = outvt + ((size_t)(bb * NH_ + hh) * DH_ + dv) * S_ + s0g;
#pragma unroll
            for (int c = 0; c < 2; ++c) {
                bf16x8 vvv = *(const bf16x8*)(LB + dd * 256 + ((ch + c * 128) ^ ((dd & 15) << 4)));
                *(bf16x8*)(dst + (ch >> 1) + c * 64) = vvv;
            }
        }
    } else {
#pragma unroll
        for (int m = 0; m < 4; ++m)
#pragma unroll
            for (int n = 0; n < 4; ++n) {
                const int col = n0 + wc * 64 + n * 16 + rl;
                const float bv = bias[col];
                const int row0 = m0 + wr * 64 + m * 16 + rg * 4;
                if (EPI == 1) {
#pragma unroll
                    for (int r = 0; r < 4; ++r) {
                        const size_t idx = (size_t)(row0 + r) * H_ + col;
                        outq[idx] = (__bf16)(acc[m][n][r] + bv + resid[idx]);
                    }
                } else {
                    const int seg = n0 >> 10;          // 0=Q, 1=K (block-uniform)
                    const int cs = col & 1023;
                    __bf16* o = (seg == 0) ? outq : outk;
#pragma unroll
                    for (int r = 0; r < 4; ++r)
                        o[(size_t)(row0 + r) * H_ + cs] = (__bf16)(acc[m][n][r] + bv);
                }
            }
    }
}

// ------------------------------------------------------------ attention ----
// Swapped QK^T + permuted-K LDS -> lane-local x32 B-fragments for PV & lsum
// (zero cross-lane). Fixed-m softmax. 32 q-rows/wave (per-work LDS reads
// unchanged), KVBLK=64 -> 32 KB dbuf -> 4 blocks/CU = 8 waves/SIMD at
// VGPR<=64 (R13 analysis: pipes 50% idle at 4 waves/SIMD). Single barrier
// per tile; counted waits; setprio around PV cluster; XCD-swizzled grid.
__global__ __launch_bounds__(512)
void attn_fwd(const __bf16* __restrict__ q, const __bf16* __restrict__ k,
              const __bf16* __restrict__ vt, const float* __restrict__ msk2,
              __bf16* __restrict__ ctx)
{
    __shared__ __align__(16) char KVs[2 * 16384];   // 32 KB: buf x (K 8K | V 8K)

    // XCD swizzle: phys%8 = XCD; 64 consecutive orig per XCD (8 heads).
    const int phys = blockIdx.x;
    const int orig = (phys & 7) * 64 + (phys >> 3);
    const int qt0 = (orig & 7) * 256;          // 8 q-tiles of 256 rows
    const int hg = orig >> 3;                  // global head 0..63
    const int h = hg & (NH_ - 1), b = hg >> 4;

    const int tid = threadIdx.x, lane = tid & 63, wv = tid >> 6;   // wv 0..7
    const int rl = lane & 15, rg = lane >> 4;
    const int swz = (rl & 7) << 4;
    const float SC = 0.125f * 1.44269504089f;      // 1/sqrt(64) * log2(e)
    const float* mptr = msk2 + (size_t)b * S_ + rg * 8;

    // Q as B-fragment (col = q = rl, k-elems dh = rg*8+j); wave owns 32 rows
    bf16x8 qf[2][2];
#pragma unroll
    for (int qm = 0; qm < 2; ++qm)
#pragma unroll
        for (int ks = 0; ks < 2; ++ks)
            qf[qm][ks] = *(const bf16x8*)(q + (size_t)(b * S_ + qt0 + wv * 32 + qm * 16 + rl) * H_
                                            + h * DH_ + ks * 32 + rg * 8);

    f32x4 cacc[2][4] = {};
    f32x4 lacc[2] = {};
    bf16x8 ones8;
#pragma unroll
    for (int i = 0; i < 8; ++i) ones8[i] = (__bf16)1.0f;

    // staging: K tile 64x128B (8KB) + V tile 64x128B (8KB); 512 thr x 16B
    // covers each in ONE gll16. Wave wv stages rows [wv*8, wv*8+8).
    const int sR = lane >> 3, sS = lane & 7;
    const __bf16* kbase = k  + (size_t)b * S_ * H_ + h * DH_;
    const __bf16* vbase = vt + (size_t)(b * NH_ + h) * DH_ * S_;

    // K-row permutation: LDS row r holds physical key perm(r) of the tile
    auto permk = [](int r) {
        return ((r >> 5) << 5) + 8 * ((r >> 2) & 3) + 4 * ((r >> 4) & 1) + (r & 3);
    };

    // running per-thread source pointers (advance per 64-key tile)
    const int krow = wv * 8 + sR;              // 0..63
    const int vrow = wv * 8 + sR;              // d row 0..63
    const __bf16* kp = kbase + (size_t)permk(krow) * H_ + 8 * (sS ^ (krow & 7));
    const __bf16* vp = vbase + (size_t)vrow * S_ + 8 * (sS ^ (vrow & 7));
    const int kd = (wv * 8) * 128;
    const int vd = 8192 + (wv * 8) * 128;

    // prologue: stage tile 0 into buf 0
    gll16(KVs + kd, kp); gll16(KVs + vd, vp);
    kp += 64 * H_; vp += 64;

    const int NT = S_ / 64;
    int cur = 0;
    for (int t = 0; t < NT; ++t) {
        // tile t landed + my prior-tile LDS reads done
        asm volatile("s_waitcnt vmcnt(0) lgkmcnt(0)" ::: "memory");
        __builtin_amdgcn_s_barrier();               // all waves: safe to reuse buf
        __builtin_amdgcn_sched_barrier(0);

        if (t + 1 < NT) {                           // stage tile t+1 into other buf
            char* nb = KVs + (cur ^ 1) * 16384;
            gll16(nb + kd, kp); gll16(nb + vd + (0 - 8192) + 8192, vp);
            kp += 64 * H_; vp += 64;
        }

        const char* Ks = KVs + cur * 16384;
        const char* Vs = Ks + 8192;
        const float* mrow = mptr + t * 64;

        // ---- per-32-key pipeline: QK(2 chunks) -> exp2/pack -> lsum+PV @x32
#pragma unroll
        for (int t4 = 0; t4 < 2; ++t4) {
            union { uint32_t u[4]; bf16x8 v; } pb0, pb1;
#pragma unroll
            for (int half = 0; half < 2; ++half) {
                const int c = 2 * t4 + half;
                bf16x8 kf0 = *(const bf16x8*)(Ks + (c * 16 + rl) * 128 + ((rg * 16) ^ swz));
                bf16x8 kf1 = *(const bf16x8*)(Ks + (c * 16 + rl) * 128 + ((64 + rg * 16) ^ swz));
                f32x4 s0 = {0, 0, 0, 0}, s1 = {0, 0, 0, 0};
                s0 = __builtin_amdgcn_mfma_f32_16x16x32_bf16(kf0, qf[0][0], s0, 0, 0, 0);
                s0 = __builtin_amdgcn_mfma_f32_16x16x32_bf16(kf1, qf[0][1], s0, 0, 0, 0);
                s1 = __builtin_amdgcn_mfma_f32_16x16x32_bf16(kf0, qf[1][0], s1, 0, 0, 0);
                s1 = __builtin_amdgcn_mfma_f32_16x16x32_bf16(kf1, qf[1][1], s1, 0, 0, 0);

                // physical keys 32*t4 + 8*rg + 4*half + {0..3}
                f32x4 m4 = *(const f32x4*)(mrow + 32 * t4 + 4 * half);
                float p0 = fast_exp2(fmaf(s0[0], SC, m4[0]));
                float p1 = fast_exp2(fmaf(s0[1], SC, m4[1]));
                float p2 = fast_exp2(fmaf(s0[2], SC, m4[2]));
                float p3 = fast_exp2(fmaf(s0[3], SC, m4[3]));
                float u0 = fast_exp2(fmaf(s1[0], SC, m4[0]));
                float u1 = fast_exp2(fmaf(s1[1], SC, m4[1]));
                float u2 = fast_exp2(fmaf(s1[2], SC, m4[2]));
                float u3 = fast_exp2(fmaf(s1[3], SC, m4[3]));
                pb0.u[half * 2]     = pack_bf16(p0, p1);
                pb0.u[half * 2 + 1] = pack_bf16(p2, p3);
                pb1.u[half * 2]     = pack_bf16(u0, u1);
                pb1.u[half * 2 + 1] = pack_bf16(u2, u3);
            }
            __builtin_amdgcn_s_setprio(1);
            lacc[0] = __builtin_amdgcn_mfma_f32_16x16x32_bf16(ones8, pb0.v, lacc[0], 0, 0, 0);
            lacc[1] = __builtin_amdgcn_mfma_f32_16x16x32_bf16(ones8, pb1.v, lacc[1], 0, 0, 0);
#pragma unroll
            for (int n = 0; n < 4; ++n) {
                bf16x8 af = *(const bf16x8*)(Vs + (n * 16 + rl) * 128 + ((t4 * 64 + rg * 16) ^ swz));
                cacc[0][n] = __builtin_amdgcn_mfma_f32_16x16x32_bf16(af, pb0.v, cacc[0][n], 0, 0, 0);
                cacc[1][n] = __builtin_amdgcn_mfma_f32_16x16x32_bf16(af, pb1.v, cacc[1][n], 0, 0, 0);
            }
            __builtin_amdgcn_s_setprio(0);
        }
        cur ^= 1;
    }

    // ---- normalize + write ctx [B,S,H] bf16 (O^T: lane has q=rl, d=rg*4+r)
#pragma unroll
    for (int qm = 0; qm < 2; ++qm) {
        const float inv = 1.f / lacc[qm][0];       // ones-MFMA: col-sum for q=rl
        const int row = qt0 + wv * 32 + qm * 16 + rl;
        __bf16* cb = ctx + (size_t)(b * S_ + row) * H_ + h * DH_;
#pragma unroll
        for (int n = 0; n < 4; ++n) {
            uint32_t u0 = pack_bf16(cacc[qm][n][0] * inv, cacc[qm][n][1] * inv);
            uint32_t u1 = pack_bf16(cacc[qm][n][2] * inv, cacc[qm][n][3] * inv);
            *(uint32_t*)(cb + n * 16 + rg * 4)     = u0;
            *(uint32_t*)(cb + n * 16 + rg * 4 + 2) = u1;
        }
    }
}

// ------------------------------------------------------------ layernorm ----
// bf16 input (pre), fp32 output.
__global__ __launch_bounds__(256)
void ln_kernel(const __bf16* __restrict__ x, const float* __restrict__ gamma,
               const float* __restrict__ beta, float* __restrict__ out)
{
    const int row = blockIdx.x;
    const int t = threadIdx.x;
    const unsigned short* xr = (const unsigned short*)(x + (size_t)row * H_);
    ushort4 raw = *(const ushort4*)(xr + t * 4);
    union { uint32_t u; float f; } c0, c1, c2, c3;
    c0.u = (uint32_t)raw.x << 16; c1.u = (uint32_t)raw.y << 16;
    c2.u = (uint32_t)raw.z << 16; c3.u = (uint32_t)raw.w << 16;
    float v0 = c0.f, v1 = c1.f, v2 = c2.f, v3 = c3.f;
    float s  = v0 + v1 + v2 + v3;
    float ss = v0 * v0 + v1 * v1 + v2 * v2 + v3 * v3;
#pragma unroll
    for (int off = 1; off < 64; off <<= 1) {
        s  += __shfl_xor(s, off, 64);
        ss += __shfl_xor(ss, off, 64);
    }
    __shared__ float sb[8];
    const int wv = t >> 6, lane = t & 63;
    if (lane == 0) { sb[wv] = s; sb[4 + wv] = ss; }
    __syncthreads();
    s  = sb[0] + sb[1] + sb[2] + sb[3];
    ss = sb[4] + sb[5] + sb[6] + sb[7];
    const float mu = s * (1.f / H_);
    const float var = ss * (1.f / H_) - mu * mu;
    const float rstd = rsqrtf(var + 1e-12f);
    float4 g = *(const float4*)(gamma + t * 4);
    float4 bt = *(const float4*)(beta + t * 4);
    float4 o;
    o.x = (v0 - mu) * rstd * g.x + bt.x;
    o.y = (v1 - mu) * rstd * g.y + bt.y;
    o.z = (v2 - mu) * rstd * g.z + bt.z;
    o.w = (v3 - mu) * rstd * g.w + bt.w;
    *(float4*)(out + (size_t)row * H_ + t * 4) = o;
}

// -------------------------------------------------------------- launch ----
extern "C" void kernel_launch(void* const* d_in, const int* in_sizes, int n_in,
                              void* d_out, int out_size, void* d_ws, size_t ws_size,
                              hipStream_t stream)
{
    const float* hs    = (const float*)d_in[0];
    const float* mask  = (const float*)d_in[1];
    const float* Wq    = (const float*)d_in[2];
    const float* bq    = (const float*)d_in[3];
    const float* Wk    = (const float*)d_in[4];
    const float* bk    = (const float*)d_in[5];
    const float* Wv    = (const float*)d_in[6];
    const float* bv    = (const float*)d_in[7];
    const float* Wo    = (const float*)d_in[8];
    const float* bo    = (const float*)d_in[9];
    const float* gamma = (const float*)d_in[10];
    const float* beta  = (const float*)d_in[11];

    char* ws = (char*)d_ws;
    const size_t MB = 1ull << 20;
    __bf16* x_bf   = (__bf16*)(ws);             // 16 MB (dead after QKV GEMM)
    __bf16* wqkv   = (__bf16*)(ws + 16 * MB);   // 6 MB concat [Wq;Wk;Wv]
    __bf16* wo_bf  = (__bf16*)(ws + 22 * MB);   // 2 MB
    __bf16* q_bf   = (__bf16*)(ws + 24 * MB);   // 16 MB (later pre_bf)
    __bf16* k_bf   = (__bf16*)(ws + 40 * MB);   // 16 MB
    __bf16* vt_bf  = (__bf16*)(ws + 56 * MB);   // 16 MB
    float*  msk2   = (float*)(ws + 72 * MB);    // 32 KB pre-scaled mask
    float*  bqkv   = (float*)(ws + 72 * MB + (64 << 10));  // 12 KB concat bias
    __bf16* ctx_bf = (__bf16*)(ws);             // aliases x_bf (x dead by then)
    __bf16* pre_bf = (__bf16*)(ws + 24 * MB);   // 16 MB, aliases q (dead by then)

    // single prep dispatch: all casts + mask prescale + bias concat
    prep_kernel<<<6160, 256, 0, stream>>>(hs, Wq, Wk, Wv, Wo, mask, bq, bk, bv,
                                          x_bf, wqkv, wo_bf, msk2, bqkv);

    // fused QKV projection: N = 3072 (seg 0=Q, 1=K, 2=V^T via LDS transpose)
    gemm_bt<3><<<dim3(3 * H_ / 128, M_ / 128), 256, 0, stream>>>(
        x_bf, wqkv, bqkv, nullptr, q_bf, k_bf, vt_bf);

    attn_fwd<<<dim3(S_ / 256 * NH_ * B_), 512, 0, stream>>>(q_bf, k_bf, vt_bf, msk2, ctx_bf);

    // Wo proj + bias + residual -> bf16 pre
    gemm_bt<1><<<dim3(H_ / 128, M_ / 128), 256, 0, stream>>>(
        ctx_bf, wo_bf, bo, hs, pre_bf, nullptr, nullptr);

    ln_kernel<<<M_, 256, 0, stream>>>(pre_bf, gamma, beta, (float*)d_out);
}

// Round 15
// 201.375 us; speedup vs baseline: 1.0246x; 1.0246x over previous
//
#include <hip/hip_runtime.h>
#include <hip/hip_bf16.h>
#include <stdint.h>

#define B_ 4
#define S_ 2048
#define H_ 1024
#define NH_ 16
#define DH_ 64
#define M_ (B_*S_)   // 8192

typedef __bf16 bf16x8 __attribute__((ext_vector_type(8)));
typedef float f32x4 __attribute__((ext_vector_type(4)));

static_assert(sizeof(__bf16) == 2, "bf16 size");

__device__ __forceinline__ uint32_t pack_bf16(float lo, float hi)
{
    union { __bf16 h[2]; uint32_t u; } t;
    t.h[0] = (__bf16)lo; t.h[1] = (__bf16)hi;
    return t.u;
}

__device__ __forceinline__ float fast_exp2(float x)
{
#if __has_builtin(__builtin_amdgcn_exp2f)
    return __builtin_amdgcn_exp2f(x);
#else
    return exp2f(x);
#endif
}

// async global->LDS, 16B per lane. LDS dest = wave-uniform base + lane*16.
__device__ __forceinline__ void gll16(void* lds, const void* g)
{
    __builtin_amdgcn_global_load_lds(
        (const __attribute__((address_space(1))) unsigned int*)g,
        (__attribute__((address_space(3))) unsigned int*)lds,
        16, 0, 0);
}

// ----------------------------------------------------------------- prep ----
__device__ __forceinline__ void cast8(const float* __restrict__ s, __bf16* __restrict__ d, int i)
{
    float4 a = *(const float4*)(s + i);
    float4 b = *(const float4*)(s + i + 4);
    bf16x8 o;
    o[0] = (__bf16)a.x; o[1] = (__bf16)a.y; o[2] = (__bf16)a.z; o[3] = (__bf16)a.w;
    o[4] = (__bf16)b.x; o[5] = (__bf16)b.y; o[6] = (__bf16)b.z; o[7] = (__bf16)b.w;
    *(bf16x8*)(d + i) = o;
}

__global__ __launch_bounds__(256)
void prep_kernel(const float* __restrict__ hs,
                 const float* __restrict__ Wq, const float* __restrict__ Wk,
                 const float* __restrict__ Wv, const float* __restrict__ Wo,
                 const float* __restrict__ mask,
                 const float* __restrict__ bq, const float* __restrict__ bk,
                 const float* __restrict__ bv,
                 __bf16* __restrict__ x_bf, __bf16* __restrict__ wqkv,
                 __bf16* __restrict__ wo_bf, float* __restrict__ msk2,
                 float* __restrict__ bqkv)
{
    const int bid = blockIdx.x, tid = threadIdx.x;
    const int nw = H_ * H_;
    if (bid < 4096) {
        cast8(hs, x_bf, bid * 2048 + tid * 8);
    } else if (bid < 4608) {
        cast8(Wq, wqkv, (bid - 4096) * 2048 + tid * 8);
    } else if (bid < 5120) {
        cast8(Wk, wqkv + nw, (bid - 4608) * 2048 + tid * 8);
    } else if (bid < 5632) {
        cast8(Wv, wqkv + 2 * nw, (bid - 5120) * 2048 + tid * 8);
    } else if (bid < 6144) {
        cast8(Wo, wo_bf, (bid - 5632) * 2048 + tid * 8);
    } else if (bid < 6148) {
        const int i = (bid - 6144) * 2048 + tid * 8;
        float4 a = *(const float4*)(mask + i);
        float4 c = *(const float4*)(mask + i + 4);
        const float L = 1.44269504089f;
        float4 sa = {a.x * L, a.y * L, a.z * L, a.w * L};
        float4 sc = {c.x * L, c.y * L, c.z * L, c.w * L};
        *(float4*)(msk2 + i)     = sa;
        *(float4*)(msk2 + i + 4) = sc;
    } else {
        const int j = (bid - 6148) * 256 + tid;
        const float* src = (j < H_) ? bq : (j < 2 * H_) ? bk : bv;
        bqkv[j] = src[j & (H_ - 1)];
    }
}

// ---------------------------------------------------------------- GEMM ----
// C[M,N] = A[M,K] @ Bw[N,K]^T + bias. bf16 in, fp32 acc. 128x128 tile,
// BK=32, FOUR-buffer LDS ring (64 KB) + 2-deep prefetch with counted
// vmcnt(4) (T4: never drain to 0 in the loop). 64B LDS rows, swizzle
// slot ^ ((row>>1)&3) (<=2-way banks, write/read involutions match).
// EPI 1: bf16 out + resid (Wo). EPI 3: fused QKV -> q, k, V^T (LDS transp).
template<int EPI>
__global__ __launch_bounds__(256)
void gemm_bt(const __bf16* __restrict__ A, const __bf16* __restrict__ Bw,
             const float* __restrict__ bias, const float* __restrict__ resid,
             __bf16* __restrict__ outq, __bf16* __restrict__ outk,
             __bf16* __restrict__ outvt)
{
    __shared__ __align__(16) char LDS[4 * 16384];   // ring: [A 8K | B 8K] x4

    const int tid  = threadIdx.x;
    const int lane = tid & 63, wv = tid >> 6;
    const int wr = wv >> 1, wc = wv & 1;           // 2x2 wave grid, 64x64 each
    const int m0 = blockIdx.y * 128, n0 = blockIdx.x * 128;
    const int rl = lane & 15, rg = lane >> 4;

    // staging: row (within 64-row group) = wv*16 + lane>>2, slot = lane&3,
    // source col pre-swizzled by (lane>>3)&3 == ((row>>1)&3)
    const int sRow = wv * 16 + (lane >> 2);
    const int sSw  = 8 * ((lane & 3) ^ ((lane >> 3) & 3));
    // read: byte-in-row = (rg ^ ((rl>>1)&3)) * 16
    const int kboff = (rg ^ ((rl >> 1) & 3)) << 4;

    f32x4 acc[4][4] = {};

    auto stage = [&](int buf, int k0) {
        char* As = LDS + buf * 16384;
#pragma unroll
        for (int p = 0; p < 2; ++p) {
            gll16(As + p * 4096 + wv * 1024,
                  A  + (size_t)(m0 + p * 64 + sRow) * H_ + k0 + sSw);
            gll16(As + 8192 + p * 4096 + wv * 1024,
                  Bw + (size_t)(n0 + p * 64 + sRow) * H_ + k0 + sSw);
        }
    };

    stage(0, 0);
    stage(1, 32);
    const int NTK = H_ / 32;                        // 32 K-tiles
    for (int t = 0; t < NTK; ++t) {
        if (t + 1 < NTK)
            asm volatile("s_waitcnt vmcnt(4) lgkmcnt(0)" ::: "memory");
        else
            asm volatile("s_waitcnt vmcnt(0) lgkmcnt(0)" ::: "memory");
        __builtin_amdgcn_s_barrier();               // tile t ready; old buf free
        __builtin_amdgcn_sched_barrier(0);
        if (t + 2 < NTK) stage((t + 2) & 3, (t + 2) * 32);

        const char* As = LDS + (t & 3) * 16384;
        const char* Bs = As + 8192;
        bf16x8 af[4], bfr[4];
#pragma unroll
        for (int n = 0; n < 4; ++n)
            bfr[n] = *(const bf16x8*)(Bs + (wc * 64 + n * 16 + rl) * 64 + kboff);
#pragma unroll
        for (int m = 0; m < 4; ++m)
            af[m] = *(const bf16x8*)(As + (wr * 64 + m * 16 + rl) * 64 + kboff);
#pragma unroll
        for (int m = 0; m < 4; ++m)
#pragma unroll
            for (int n = 0; n < 4; ++n)
                acc[m][n] = __builtin_amdgcn_mfma_f32_16x16x32_bf16(af[m], bfr[n], acc[m][n], 0, 0, 0);
    }
    __syncthreads();                                // LDS reusable by epilogue

    // epilogue: C/D layout col = lane&15, row = (lane>>4)*4 + reg   [m89]
    if (EPI == 3 && (n0 >> 10) == 2) {
        // ---- V^T: transpose the 128x128 tile in LDS (XOR-swizzled), then
        //      coalesced 16B stores (row = d, contiguous in s).
#pragma unroll
        for (int m = 0; m < 4; ++m)
#pragma unroll
            for (int n = 0; n < 4; ++n) {
                const int lcol = wc * 64 + n * 16 + rl;      // local d
                const int ls0  = wr * 64 + m * 16 + rg * 4;  // local s
                const float bv = bias[n0 + lcol];
                uint32_t w0 = pack_bf16(acc[m][n][0] + bv, acc[m][n][1] + bv);
                uint32_t w1 = pack_bf16(acc[m][n][2] + bv, acc[m][n][3] + bv);
                const int xorv = (lcol & 15) << 4;
                *(uint32_t*)(LDS + lcol * 256 + ((ls0 * 2) ^ xorv))       = w0;
                *(uint32_t*)(LDS + lcol * 256 + (((ls0 + 2) * 2) ^ xorv)) = w1;
            }
        __syncthreads();
        const int bb = m0 >> 11, s0g = m0 & (S_ - 1);
#pragma unroll
        for (int pass = 0; pass < 4; ++pass) {
            const int dd = pass * 32 + wv * 8 + (lane >> 3);
            const int ch = (lane & 7) * 16;                  // byte chunk in row
            const int cs = (n0 & 1023) + dd;
            const int hh = cs >> 6, dv = cs & 63;
            __bf16* dst = outvt + ((size_t)(bb * NH_ + hh) * DH_ + dv) * S_ + s0g;
#pragma unroll
            for (int c = 0; c < 2; ++c) {
                bf16x8 vvv = *(const bf16x8*)(LDS + dd * 256 + ((ch + c * 128) ^ ((dd & 15) << 4)));
                *(bf16x8*)(dst + (ch >> 1) + c * 64) = vvv;
            }
        }
    } else {
#pragma unroll
        for (int m = 0; m < 4; ++m)
#pragma unroll
            for (int n = 0; n < 4; ++n) {
                const int col = n0 + wc * 64 + n * 16 + rl;
                const float bv = bias[col];
                const int row0 = m0 + wr * 64 + m * 16 + rg * 4;
                if (EPI == 1) {
#pragma unroll
                    for (int r = 0; r < 4; ++r) {
                        const size_t idx = (size_t)(row0 + r) * H_ + col;
                        outq[idx] = (__bf16)(acc[m][n][r] + bv + resid[idx]);
                    }
                } else {
                    const int seg = n0 >> 10;          // 0=Q, 1=K (block-uniform)
                    const int cs = col & 1023;
                    __bf16* o = (seg == 0) ? outq : outk;
#pragma unroll
                    for (int r = 0; r < 4; ++r)
                        o[(size_t)(row0 + r) * H_ + cs] = (__bf16)(acc[m][n][r] + bv);
                }
            }
    }
}

// ------------------------------------------------------------ attention ----
// R13 structure (best measured: 91.5 us). Swapped QK^T + permuted-K LDS ->
// lane-local x32 B-fragments for PV & lsum (zero cross-lane). Fixed-m
// softmax. 32 q-rows/wave, 8-wave blocks (256 rows), KVBLK=128, 64 KB dbuf
// LDS, single barrier/tile + counted waits, setprio around PV cluster,
// XCD-swizzled 512-block grid.
__global__ __launch_bounds__(512)
void attn_fwd(const __bf16* __restrict__ q, const __bf16* __restrict__ k,
              const __bf16* __restrict__ vt, const float* __restrict__ msk2,
              __bf16* __restrict__ ctx)
{
    __shared__ __align__(16) char KVs[2 * 32768];   // 64 KB exactly

    // XCD swizzle: phys%8 = XCD; 64 consecutive orig per XCD (8 heads).
    const int phys = blockIdx.x;
    const int orig = (phys & 7) * 64 + (phys >> 3);
    const int qt0 = (orig & 7) * 256;          // 8 q-tiles of 256 rows
    const int hg = orig >> 3;                  // global head 0..63
    const int h = hg & (NH_ - 1), b = hg >> 4;

    const int tid = threadIdx.x, lane = tid & 63, wv = tid >> 6;   // wv 0..7
    const int rl = lane & 15, rg = lane >> 4;
    const int swz = (rl & 7) << 4;
    const float SC = 0.125f * 1.44269504089f;      // 1/sqrt(64) * log2(e)
    const float* mptr = msk2 + (size_t)b * S_ + rg * 8;

    // Q as B-fragment (col = q = rl, k-elems dh = rg*8+j); wave owns 32 rows
    bf16x8 qf[2][2];
#pragma unroll
    for (int qm = 0; qm < 2; ++qm)
#pragma unroll
        for (int ks = 0; ks < 2; ++ks)
            qf[qm][ks] = *(const bf16x8*)(q + (size_t)(b * S_ + qt0 + wv * 32 + qm * 16 + rl) * H_
                                            + h * DH_ + ks * 32 + rg * 8);

    f32x4 cacc[2][4] = {};
    f32x4 lacc[2] = {};
    bf16x8 ones8;
#pragma unroll
    for (int i = 0; i < 8; ++i) ones8[i] = (__bf16)1.0f;

    // staging geometry (8 waves: 2 gll16 rounds each for K and V)
    const int kR = lane >> 3, kS = lane & 7;       // K: 8 rows/inst, 8 slots
    const int vR = lane >> 4, vS = lane & 15;      // V: 4 rows/inst, 16 slots
    const __bf16* kbase = k  + (size_t)b * S_ * H_ + h * DH_;
    const __bf16* vbase = vt + (size_t)(b * NH_ + h) * DH_ * S_;

    // K-row permutation: LDS row r holds physical key perm(r) of the tile
    auto permk = [](int r) {
        return ((r >> 5) << 5) + 8 * ((r >> 2) & 3) + 4 * ((r >> 4) & 1) + (r & 3);
    };

    // running per-thread source pointers (advance per tile)
    const int krow0 = wv * 8 + kR, krow1 = 64 + krow0;
    const int vrow0 = wv * 4 + vR, vrow1 = 32 + vrow0;
    const __bf16* kp0 = kbase + (size_t)permk(krow0) * H_ + 8 * (kS ^ (krow0 & 7));
    const __bf16* kp1 = kbase + (size_t)permk(krow1) * H_ + 8 * (kS ^ (krow1 & 7));
    const __bf16* vp0 = vbase + (size_t)vrow0 * S_ + 8 * (vS ^ (vrow0 & 7));
    const __bf16* vp1 = vbase + (size_t)vrow1 * S_ + 8 * (vS ^ (vrow1 & 7));
    const int kd0 = (wv * 8) * 128, kd1 = (64 + wv * 8) * 128;
    const int vd0 = 16384 + (wv * 4) * 256, vd1 = 16384 + (32 + wv * 4) * 256;

    // prologue: stage tile 0 into buf 0
    gll16(KVs + kd0, kp0); gll16(KVs + kd1, kp1);
    gll16(KVs + vd0, vp0); gll16(KVs + vd1, vp1);
    kp0 += 128 * H_; kp1 += 128 * H_; vp0 += 128; vp1 += 128;

    const int NT = S_ / 128;
    int cur = 0;
    for (int t = 0; t < NT; ++t) {
        // tile t landed (issued a full tile ago) + my prior-tile LDS reads done
        asm volatile("s_waitcnt vmcnt(0) lgkmcnt(0)" ::: "memory");
        __builtin_amdgcn_s_barrier();               // all waves: safe to reuse buf
        __builtin_amdgcn_sched_barrier(0);

        if (t + 1 < NT) {                           // stage tile t+1 into other buf
            char* nb = KVs + (cur ^ 1) * 32768;
            gll16(nb + kd0, kp0); gll16(nb + kd1, kp1);
            gll16(nb + vd0, vp0); gll16(nb + vd1, vp1);
            kp0 += 128 * H_; kp1 += 128 * H_; vp0 += 128; vp1 += 128;
        }

        const char* Ks = KVs + cur * 32768;
        const char* Vs = Ks + 16384;
        const float* mrow = mptr + t * 128;

        // ---- per-32-key pipeline: QK(2 chunks) -> exp2/pack -> lsum+PV @x32
#pragma unroll
        for (int t4 = 0; t4 < 4; ++t4) {
            union { uint32_t u[4]; bf16x8 v; } pb0, pb1;
#pragma unroll
            for (int half = 0; half < 2; ++half) {
                const int c = 2 * t4 + half;
                bf16x8 kf0 = *(const bf16x8*)(Ks + (c * 16 + rl) * 128 + ((rg * 16) ^ swz));
                bf16x8 kf1 = *(const bf16x8*)(Ks + (c * 16 + rl) * 128 + ((64 + rg * 16) ^ swz));
                f32x4 s0 = {0, 0, 0, 0}, s1 = {0, 0, 0, 0};
                s0 = __builtin_amdgcn_mfma_f32_16x16x32_bf16(kf0, qf[0][0], s0, 0, 0, 0);
                s0 = __builtin_amdgcn_mfma_f32_16x16x32_bf16(kf1, qf[0][1], s0, 0, 0, 0);
                s1 = __builtin_amdgcn_mfma_f32_16x16x32_bf16(kf0, qf[1][0], s1, 0, 0, 0);
                s1 = __builtin_amdgcn_mfma_f32_16x16x32_bf16(kf1, qf[1][1], s1, 0, 0, 0);

                // physical keys 32*t4 + 8*rg + 4*half + {0..3}
                f32x4 m4 = *(const f32x4*)(mrow + 32 * t4 + 4 * half);
                float p0 = fast_exp2(fmaf(s0[0], SC, m4[0]));
                float p1 = fast_exp2(fmaf(s0[1], SC, m4[1]));
                float p2 = fast_exp2(fmaf(s0[2], SC, m4[2]));
                float p3 = fast_exp2(fmaf(s0[3], SC, m4[3]));
                float u0 = fast_exp2(fmaf(s1[0], SC, m4[0]));
                float u1 = fast_exp2(fmaf(s1[1], SC, m4[1]));
                float u2 = fast_exp2(fmaf(s1[2], SC, m4[2]));
                float u3 = fast_exp2(fmaf(s1[3], SC, m4[3]));
                pb0.u[half * 2]     = pack_bf16(p0, p1);
                pb0.u[half * 2 + 1] = pack_bf16(p2, p3);
                pb1.u[half * 2]     = pack_bf16(u0, u1);
                pb1.u[half * 2 + 1] = pack_bf16(u2, u3);
            }
            __builtin_amdgcn_s_setprio(1);
            lacc[0] = __builtin_amdgcn_mfma_f32_16x16x32_bf16(ones8, pb0.v, lacc[0], 0, 0, 0);
            lacc[1] = __builtin_amdgcn_mfma_f32_16x16x32_bf16(ones8, pb1.v, lacc[1], 0, 0, 0);
#pragma unroll
            for (int n = 0; n < 4; ++n) {
                bf16x8 af = *(const bf16x8*)(Vs + (n * 16 + rl) * 256 + ((t4 * 64 + rg * 16) ^ swz));
                cacc[0][n] = __builtin_amdgcn_mfma_f32_16x16x32_bf16(af, pb0.v, cacc[0][n], 0, 0, 0);
                cacc[1][n] = __builtin_amdgcn_mfma_f32_16x16x32_bf16(af, pb1.v, cacc[1][n], 0, 0, 0);
            }
            __builtin_amdgcn_s_setprio(0);
        }
        cur ^= 1;
    }

    // ---- normalize + write ctx [B,S,H] bf16 (O^T: lane has q=rl, d=rg*4+r)
#pragma unroll
    for (int qm = 0; qm < 2; ++qm) {
        const float inv = 1.f / lacc[qm][0];       // ones-MFMA: col-sum for q=rl
        const int row = qt0 + wv * 32 + qm * 16 + rl;
        __bf16* cb = ctx + (size_t)(b * S_ + row) * H_ + h * DH_;
#pragma unroll
        for (int n = 0; n < 4; ++n) {
            uint32_t u0 = pack_bf16(cacc[qm][n][0] * inv, cacc[qm][n][1] * inv);
            uint32_t u1 = pack_bf16(cacc[qm][n][2] * inv, cacc[qm][n][3] * inv);
            *(uint32_t*)(cb + n * 16 + rg * 4)     = u0;
            *(uint32_t*)(cb + n * 16 + rg * 4 + 2) = u1;
        }
    }
}

// ------------------------------------------------------------ layernorm ----
// bf16 input (pre), fp32 output.
__global__ __launch_bounds__(256)
void ln_kernel(const __bf16* __restrict__ x, const float* __restrict__ gamma,
               const float* __restrict__ beta, float* __restrict__ out)
{
    const int row = blockIdx.x;
    const int t = threadIdx.x;
    const unsigned short* xr = (const unsigned short*)(x + (size_t)row * H_);
    ushort4 raw = *(const ushort4*)(xr + t * 4);
    union { uint32_t u; float f; } c0, c1, c2, c3;
    c0.u = (uint32_t)raw.x << 16; c1.u = (uint32_t)raw.y << 16;
    c2.u = (uint32_t)raw.z << 16; c3.u = (uint32_t)raw.w << 16;
    float v0 = c0.f, v1 = c1.f, v2 = c2.f, v3 = c3.f;
    float s  = v0 + v1 + v2 + v3;
    float ss = v0 * v0 + v1 * v1 + v2 * v2 + v3 * v3;
#pragma unroll
    for (int off = 1; off < 64; off <<= 1) {
        s  += __shfl_xor(s, off, 64);
        ss += __shfl_xor(ss, off, 64);
    }
    __shared__ float sb[8];
    const int wv = t >> 6, lane = t & 63;
    if (lane == 0) { sb[wv] = s; sb[4 + wv] = ss; }
    __syncthreads();
    s  = sb[0] + sb[1] + sb[2] + sb[3];
    ss = sb[4] + sb[5] + sb[6] + sb[7];
    const float mu = s * (1.f / H_);
    const float var = ss * (1.f / H_) - mu * mu;
    const float rstd = rsqrtf(var + 1e-12f);
    float4 g = *(const float4*)(gamma + t * 4);
    float4 bt = *(const float4*)(beta + t * 4);
    float4 o;
    o.x = (v0 - mu) * rstd * g.x + bt.x;
    o.y = (v1 - mu) * rstd * g.y + bt.y;
    o.z = (v2 - mu) * rstd * g.z + bt.z;
    o.w = (v3 - mu) * rstd * g.w + bt.w;
    *(float4*)(out + (size_t)row * H_ + t * 4) = o;
}

// -------------------------------------------------------------- launch ----
extern "C" void kernel_launch(void* const* d_in, const int* in_sizes, int n_in,
                              void* d_out, int out_size, void* d_ws, size_t ws_size,
                              hipStream_t stream)
{
    const float* hs    = (const float*)d_in[0];
    const float* mask  = (const float*)d_in[1];
    const float* Wq    = (const float*)d_in[2];
    const float* bq    = (const float*)d_in[3];
    const float* Wk    = (const float*)d_in[4];
    const float* bk    = (const float*)d_in[5];
    const float* Wv    = (const float*)d_in[6];
    const float* bv    = (const float*)d_in[7];
    const float* Wo    = (const float*)d_in[8];
    const float* bo    = (const float*)d_in[9];
    const float* gamma = (const float*)d_in[10];
    const float* beta  = (const float*)d_in[11];

    char* ws = (char*)d_ws;
    const size_t MB = 1ull << 20;
    __bf16* x_bf   = (__bf16*)(ws);             // 16 MB (dead after QKV GEMM)
    __bf16* wqkv   = (__bf16*)(ws + 16 * MB);   // 6 MB concat [Wq;Wk;Wv]
    __bf16* wo_bf  = (__bf16*)(ws + 22 * MB);   // 2 MB
    __bf16* q_bf   = (__bf16*)(ws + 24 * MB);   // 16 MB (later pre_bf)
    __bf16* k_bf   = (__bf16*)(ws + 40 * MB);   // 16 MB
    __bf16* vt_bf  = (__bf16*)(ws + 56 * MB);   // 16 MB
    float*  msk2   = (float*)(ws + 72 * MB);    // 32 KB pre-scaled mask
    float*  bqkv   = (float*)(ws + 72 * MB + (64 << 10));  // 12 KB concat bias
    __bf16* ctx_bf = (__bf16*)(ws);             // aliases x_bf (x dead by then)
    __bf16* pre_bf = (__bf16*)(ws + 24 * MB);   // 16 MB, aliases q (dead by then)

    // single prep dispatch: all casts + mask prescale + bias concat
    prep_kernel<<<6160, 256, 0, stream>>>(hs, Wq, Wk, Wv, Wo, mask, bq, bk, bv,
                                          x_bf, wqkv, wo_bf, msk2, bqkv);

    // fused QKV projection: N = 3072 (seg 0=Q, 1=K, 2=V^T via LDS transpose)
    gemm_bt<3><<<dim3(3 * H_ / 128, M_ / 128), 256, 0, stream>>>(
        x_bf, wqkv, bqkv, nullptr, q_bf, k_bf, vt_bf);

    attn_fwd<<<dim3(S_ / 256 * NH_ * B_), 512, 0, stream>>>(q_bf, k_bf, vt_bf, msk2, ctx_bf);

    // Wo proj + bias + residual -> bf16 pre
    gemm_bt<1><<<dim3(H_ / 128, M_ / 128), 256, 0, stream>>>(
        ctx_bf, wo_bf, bo, hs, pre_bf, nullptr, nullptr);

    ln_kernel<<<M_, 256, 0, stream>>>(pre_bf, gamma, beta, (float*)d_out);
}

// Round 16
// 200.353 us; speedup vs baseline: 1.0298x; 1.0051x over previous
//
#include <hip/hip_runtime.h>
#include <hip/hip_bf16.h>
#include <stdint.h>

#define B_ 4
#define S_ 2048
#define H_ 1024
#define NH_ 16
#define DH_ 64
#define M_ (B_*S_)   // 8192

typedef __bf16 bf16x8 __attribute__((ext_vector_type(8)));
typedef float f32x4 __attribute__((ext_vector_type(4)));

static_assert(sizeof(__bf16) == 2, "bf16 size");

__device__ __forceinline__ uint32_t pack_bf16(float lo, float hi)
{
    union { __bf16 h[2]; uint32_t u; } t;
    t.h[0] = (__bf16)lo; t.h[1] = (__bf16)hi;
    return t.u;
}

__device__ __forceinline__ float fast_exp2(float x)
{
#if __has_builtin(__builtin_amdgcn_exp2f)
    return __builtin_amdgcn_exp2f(x);
#else
    return exp2f(x);
#endif
}

// async global->LDS, 16B per lane. LDS dest = wave-uniform base + lane*16.
__device__ __forceinline__ void gll16(void* lds, const void* g)
{
    __builtin_amdgcn_global_load_lds(
        (const __attribute__((address_space(1))) unsigned int*)g,
        (__attribute__((address_space(3))) unsigned int*)lds,
        16, 0, 0);
}

// ----------------------------------------------------------------- prep ----
__device__ __forceinline__ void cast8(const float* __restrict__ s, __bf16* __restrict__ d, int i)
{
    float4 a = *(const float4*)(s + i);
    float4 b = *(const float4*)(s + i + 4);
    bf16x8 o;
    o[0] = (__bf16)a.x; o[1] = (__bf16)a.y; o[2] = (__bf16)a.z; o[3] = (__bf16)a.w;
    o[4] = (__bf16)b.x; o[5] = (__bf16)b.y; o[6] = (__bf16)b.z; o[7] = (__bf16)b.w;
    *(bf16x8*)(d + i) = o;
}

__global__ __launch_bounds__(256)
void prep_kernel(const float* __restrict__ hs,
                 const float* __restrict__ Wq, const float* __restrict__ Wk,
                 const float* __restrict__ Wv, const float* __restrict__ Wo,
                 const float* __restrict__ mask,
                 const float* __restrict__ bq, const float* __restrict__ bk,
                 const float* __restrict__ bv,
                 __bf16* __restrict__ x_bf, __bf16* __restrict__ wqkv,
                 __bf16* __restrict__ wo_bf, float* __restrict__ msk2,
                 float* __restrict__ bqkv)
{
    const int bid = blockIdx.x, tid = threadIdx.x;
    const int nw = H_ * H_;
    if (bid < 4096) {
        cast8(hs, x_bf, bid * 2048 + tid * 8);
    } else if (bid < 4608) {
        cast8(Wq, wqkv, (bid - 4096) * 2048 + tid * 8);
    } else if (bid < 5120) {
        cast8(Wk, wqkv + nw, (bid - 4608) * 2048 + tid * 8);
    } else if (bid < 5632) {
        cast8(Wv, wqkv + 2 * nw, (bid - 5120) * 2048 + tid * 8);
    } else if (bid < 6144) {
        cast8(Wo, wo_bf, (bid - 5632) * 2048 + tid * 8);
    } else if (bid < 6148) {
        const int i = (bid - 6144) * 2048 + tid * 8;
        float4 a = *(const float4*)(mask + i);
        float4 c = *(const float4*)(mask + i + 4);
        const float L = 1.44269504089f;
        float4 sa = {a.x * L, a.y * L, a.z * L, a.w * L};
        float4 sc = {c.x * L, c.y * L, c.z * L, c.w * L};
        *(float4*)(msk2 + i)     = sa;
        *(float4*)(msk2 + i + 4) = sc;
    } else {
        const int j = (bid - 6148) * 256 + tid;
        const float* src = (j < H_) ? bq : (j < 2 * H_) ? bk : bv;
        bqkv[j] = src[j & (H_ - 1)];
    }
}

// ------------------------------------------------- QKV GEMM (256^2 tile) ----
// C[M,3072] = x @ Wqkv^T + b. 256x256 tile, BK=32, 8 waves (2Mx4N, per-wave
// 128x64), 4-buffer LDS ring (128 KB), 2-deep prefetch, counted vmcnt(4)
// (T4: never drain in loop), per-phase {ds_read || gll16 -> barrier ->
// lgkmcnt(0)+sched_barrier -> setprio MFMA} (T3/T5). Seg epilogue:
// 0=Q, 1=K scalar; 2=V^T via 128KB LDS transpose, coalesced stores.
__global__ __launch_bounds__(512, 2)
void gemm_qkv256(const __bf16* __restrict__ A, const __bf16* __restrict__ Bw,
                 const float* __restrict__ bias, __bf16* __restrict__ outq,
                 __bf16* __restrict__ outk, __bf16* __restrict__ outvt)
{
    __shared__ __align__(16) char LDS[4 * 32768];   // ring: [A 16K | B 16K] x4

    const int tid  = threadIdx.x;
    const int lane = tid & 63, wv = tid >> 6;
    const int wr = wv >> 2, wc = wv & 3;           // 2x4 wave grid, 128x64 each
    const int m0 = blockIdx.y * 256, n0 = blockIdx.x * 256;
    const int rl = lane & 15, rg = lane >> 4;

    // staging: row = tid>>2 (0..127), slot = tid&3; swizzle w = (row>>1)&3
    const int sRow = tid >> 2;
    const int sSw  = 8 * ((tid & 3) ^ ((tid >> 3) & 3));   // source elem offset
    // read swizzle: byte-in-row = (rg ^ ((rl>>1)&3)) * 16
    const int kboff = (rg ^ ((rl >> 1) & 3)) << 4;

    f32x4 acc[8][4] = {};

    auto stage = [&](int buf, int t) {             // 4 gll16: A rows 0..255, B rows 0..255
        char* base = LDS + buf * 32768;
        const int k0 = t * 32;
#pragma unroll
        for (int r = 0; r < 2; ++r) {
            gll16(base + r * 8192 + wv * 1024,
                  A  + (size_t)(m0 + r * 128 + sRow) * H_ + k0 + sSw);
            gll16(base + 16384 + r * 8192 + wv * 1024,
                  Bw + (size_t)(n0 + r * 128 + sRow) * H_ + k0 + sSw);
        }
    };

    stage(0, 0);
    stage(1, 1);
    const int NTK = H_ / 32;                       // 32 K-tiles
    for (int t = 0; t < NTK; ++t) {
        if (t + 1 < NTK)
            asm volatile("s_waitcnt vmcnt(4)" ::: "memory");   // tile t landed
        else
            asm volatile("s_waitcnt vmcnt(0)" ::: "memory");
        __builtin_amdgcn_s_barrier();              // all waves' portions landed
        __builtin_amdgcn_sched_barrier(0);

        const char* As = LDS + (t & 3) * 32768;
        const char* Bs = As + 16384;
        const bool pf = (t + 2) < NTK;
        char* nb = LDS + ((t + 2) & 3) * 32768;
        const int nk0 = (t + 2) * 32;

        // B-frags once per tile (shared by both phases)
        bf16x8 bfr[4];
#pragma unroll
        for (int n = 0; n < 4; ++n)
            bfr[n] = *(const bf16x8*)(Bs + (wc * 64 + n * 16 + rl) * 64 + kboff);

#pragma unroll
        for (int ph = 0; ph < 2; ++ph) {
            bf16x8 af[4];
#pragma unroll
            for (int i = 0; i < 4; ++i)
                af[i] = *(const bf16x8*)(As + (wr * 128 + (ph * 4 + i) * 16 + rl) * 64 + kboff);
            if (pf) {                              // 2 gll16 of tile t+2
                gll16(nb + (ph ? 16384 : 0) + wv * 1024,
                      (ph ? Bw : A) + (size_t)((ph ? n0 : m0) + sRow) * H_ + nk0 + sSw);
                gll16(nb + (ph ? 16384 : 0) + 8192 + wv * 1024,
                      (ph ? Bw : A) + (size_t)((ph ? n0 : m0) + 128 + sRow) * H_ + nk0 + sSw);
            }
            __builtin_amdgcn_s_barrier();          // lockstep (template)
            asm volatile("s_waitcnt lgkmcnt(0)" ::: "memory");
            __builtin_amdgcn_sched_barrier(0);
            __builtin_amdgcn_s_setprio(1);
#pragma unroll
            for (int i = 0; i < 4; ++i)
#pragma unroll
                for (int n = 0; n < 4; ++n)
                    acc[ph * 4 + i][n] = __builtin_amdgcn_mfma_f32_16x16x32_bf16(
                        af[i], bfr[n], acc[ph * 4 + i][n], 0, 0, 0);
            __builtin_amdgcn_s_setprio(0);
        }
    }
    __syncthreads();                               // LDS reusable by epilogue

    const int seg = n0 >> 10;                      // block-uniform: 0=Q,1=K,2=V^T
    if (seg < 2) {
        __bf16* o = (seg == 0) ? outq : outk;
#pragma unroll
        for (int m = 0; m < 8; ++m)
#pragma unroll
            for (int n = 0; n < 4; ++n) {
                const int col = n0 + wc * 64 + n * 16 + rl;
                const float bv = bias[col];
                const int cs = col & 1023;
                const int row0 = m0 + wr * 128 + m * 16 + rg * 4;
#pragma unroll
                for (int r = 0; r < 4; ++r)
                    o[(size_t)(row0 + r) * H_ + cs] = (__bf16)(acc[m][n][r] + bv);
            }
    } else {
        // V^T: transpose 256x256 tile in LDS (rows = d, 512B, XOR (d&15)<<5)
#pragma unroll
        for (int m = 0; m < 8; ++m)
#pragma unroll
            for (int n = 0; n < 4; ++n) {
                const int lcol = wc * 64 + n * 16 + rl;      // local d 0..255
                const int ls0  = wr * 128 + m * 16 + rg * 4; // local s 0..252
                const float bv = bias[n0 + lcol];
                uint32_t w0 = pack_bf16(acc[m][n][0] + bv, acc[m][n][1] + bv);
                uint32_t w1 = pack_bf16(acc[m][n][2] + bv, acc[m][n][3] + bv);
                const int xorv = (lcol & 15) << 5;
                *(uint32_t*)(LDS + lcol * 512 + ((ls0 * 2) ^ xorv))       = w0;
                *(uint32_t*)(LDS + lcol * 512 + (((ls0 + 2) * 2) ^ xorv)) = w1;
            }
        __syncthreads();
        const int bb = m0 >> 11, s0g = m0 & (S_ - 1);
#pragma unroll
        for (int pass = 0; pass < 8; ++pass) {
            const int dd = pass * 32 + (tid >> 4);           // local d
            const int ch = (tid & 15) * 32;                  // byte chunk (32B)
            const int cs = (n0 & 1023) + dd;
            const int hh = cs >> 6, dv = cs & 63;
            __bf16* dst = outvt + ((size_t)(bb * NH_ + hh) * DH_ + dv) * S_ + s0g;
            bf16x8 v0 = *(const bf16x8*)(LDS + dd * 512 + (ch ^ ((dd & 15) << 5)));
            bf16x8 v1 = *(const bf16x8*)(LDS + dd * 512 + ((ch + 16) ^ ((dd & 15) << 5)));
            *(bf16x8*)(dst + (ch >> 1))     = v0;
            *(bf16x8*)(dst + (ch >> 1) + 8) = v1;
        }
    }
}

// ----------------------------------------------------- Wo GEMM (128^2) ----
// C = ctx @ Wo^T + bo + resid -> bf16. BK=32, 4-buffer ring, counted vmcnt.
__global__ __launch_bounds__(256)
void gemm_wo(const __bf16* __restrict__ A, const __bf16* __restrict__ Bw,
             const float* __restrict__ bias, const float* __restrict__ resid,
             __bf16* __restrict__ outp)
{
    __shared__ __align__(16) char LDS[4 * 16384];   // ring: [A 8K | B 8K] x4

    const int tid  = threadIdx.x;
    const int lane = tid & 63, wv = tid >> 6;
    const int wr = wv >> 1, wc = wv & 1;
    const int m0 = blockIdx.y * 128, n0 = blockIdx.x * 128;
    const int rl = lane & 15, rg = lane >> 4;

    const int sRow = wv * 16 + (lane >> 2);
    const int sSw  = 8 * ((lane & 3) ^ ((lane >> 3) & 3));
    const int kboff = (rg ^ ((rl >> 1) & 3)) << 4;

    f32x4 acc[4][4] = {};

    auto stage = [&](int buf, int k0) {
        char* As = LDS + buf * 16384;
#pragma unroll
        for (int p = 0; p < 2; ++p) {
            gll16(As + p * 4096 + wv * 1024,
                  A  + (size_t)(m0 + p * 64 + sRow) * H_ + k0 + sSw);
            gll16(As + 8192 + p * 4096 + wv * 1024,
                  Bw + (size_t)(n0 + p * 64 + sRow) * H_ + k0 + sSw);
        }
    };

    stage(0, 0);
    stage(1, 32);
    const int NTK = H_ / 32;
    for (int t = 0; t < NTK; ++t) {
        if (t + 1 < NTK)
            asm volatile("s_waitcnt vmcnt(4) lgkmcnt(0)" ::: "memory");
        else
            asm volatile("s_waitcnt vmcnt(0) lgkmcnt(0)" ::: "memory");
        __builtin_amdgcn_s_barrier();
        __builtin_amdgcn_sched_barrier(0);
        if (t + 2 < NTK) stage((t + 2) & 3, (t + 2) * 32);

        const char* As = LDS + (t & 3) * 16384;
        const char* Bs = As + 8192;
        bf16x8 af[4], bfr[4];
#pragma unroll
        for (int n = 0; n < 4; ++n)
            bfr[n] = *(const bf16x8*)(Bs + (wc * 64 + n * 16 + rl) * 64 + kboff);
#pragma unroll
        for (int m = 0; m < 4; ++m)
            af[m] = *(const bf16x8*)(As + (wr * 64 + m * 16 + rl) * 64 + kboff);
#pragma unroll
        for (int m = 0; m < 4; ++m)
#pragma unroll
            for (int n = 0; n < 4; ++n)
                acc[m][n] = __builtin_amdgcn_mfma_f32_16x16x32_bf16(af[m], bfr[n], acc[m][n], 0, 0, 0);
    }

#pragma unroll
    for (int m = 0; m < 4; ++m)
#pragma unroll
        for (int n = 0; n < 4; ++n) {
            const int col = n0 + wc * 64 + n * 16 + rl;
            const float bv = bias[col];
            const int row0 = m0 + wr * 64 + m * 16 + rg * 4;
#pragma unroll
            for (int r = 0; r < 4; ++r) {
                const size_t idx = (size_t)(row0 + r) * H_ + col;
                outp[idx] = (__bf16)(acc[m][n][r] + bv + resid[idx]);
            }
        }
}

// ------------------------------------------------------------ attention ----
// R13 structure (best measured: 91.5 us). Swapped QK^T + permuted-K LDS ->
// lane-local x32 B-fragments for PV & lsum (zero cross-lane). Fixed-m
// softmax. 32 q-rows/wave, 8-wave blocks (256 rows), KVBLK=128, 64 KB dbuf
// LDS, single barrier/tile + counted waits, setprio around PV cluster,
// XCD-swizzled 512-block grid.
__global__ __launch_bounds__(512)
void attn_fwd(const __bf16* __restrict__ q, const __bf16* __restrict__ k,
              const __bf16* __restrict__ vt, const float* __restrict__ msk2,
              __bf16* __restrict__ ctx)
{
    __shared__ __align__(16) char KVs[2 * 32768];   // 64 KB exactly

    const int phys = blockIdx.x;
    const int orig = (phys & 7) * 64 + (phys >> 3);
    const int qt0 = (orig & 7) * 256;
    const int hg = orig >> 3;
    const int h = hg & (NH_ - 1), b = hg >> 4;

    const int tid = threadIdx.x, lane = tid & 63, wv = tid >> 6;
    const int rl = lane & 15, rg = lane >> 4;
    const int swz = (rl & 7) << 4;
    const float SC = 0.125f * 1.44269504089f;
    const float* mptr = msk2 + (size_t)b * S_ + rg * 8;

    bf16x8 qf[2][2];
#pragma unroll
    for (int qm = 0; qm < 2; ++qm)
#pragma unroll
        for (int ks = 0; ks < 2; ++ks)
            qf[qm][ks] = *(const bf16x8*)(q + (size_t)(b * S_ + qt0 + wv * 32 + qm * 16 + rl) * H_
                                            + h * DH_ + ks * 32 + rg * 8);

    f32x4 cacc[2][4] = {};
    f32x4 lacc[2] = {};
    bf16x8 ones8;
#pragma unroll
    for (int i = 0; i < 8; ++i) ones8[i] = (__bf16)1.0f;

    const int kR = lane >> 3, kS = lane & 7;
    const int vR = lane >> 4, vS = lane & 15;
    const __bf16* kbase = k  + (size_t)b * S_ * H_ + h * DH_;
    const __bf16* vbase = vt + (size_t)(b * NH_ + h) * DH_ * S_;

    auto permk = [](int r) {
        return ((r >> 5) << 5) + 8 * ((r >> 2) & 3) + 4 * ((r >> 4) & 1) + (r & 3);
    };

    const int krow0 = wv * 8 + kR, krow1 = 64 + krow0;
    const int vrow0 = wv * 4 + vR, vrow1 = 32 + vrow0;
    const __bf16* kp0 = kbase + (size_t)permk(krow0) * H_ + 8 * (kS ^ (krow0 & 7));
    const __bf16* kp1 = kbase + (size_t)permk(krow1) * H_ + 8 * (kS ^ (krow1 & 7));
    const __bf16* vp0 = vbase + (size_t)vrow0 * S_ + 8 * (vS ^ (vrow0 & 7));
    const __bf16* vp1 = vbase + (size_t)vrow1 * S_ + 8 * (vS ^ (vrow1 & 7));
    const int kd0 = (wv * 8) * 128, kd1 = (64 + wv * 8) * 128;
    const int vd0 = 16384 + (wv * 4) * 256, vd1 = 16384 + (32 + wv * 4) * 256;

    gll16(KVs + kd0, kp0); gll16(KVs + kd1, kp1);
    gll16(KVs + vd0, vp0); gll16(KVs + vd1, vp1);
    kp0 += 128 * H_; kp1 += 128 * H_; vp0 += 128; vp1 += 128;

    const int NT = S_ / 128;
    int cur = 0;
    for (int t = 0; t < NT; ++t) {
        asm volatile("s_waitcnt vmcnt(0) lgkmcnt(0)" ::: "memory");
        __builtin_amdgcn_s_barrier();
        __builtin_amdgcn_sched_barrier(0);

        if (t + 1 < NT) {
            char* nb = KVs + (cur ^ 1) * 32768;
            gll16(nb + kd0, kp0); gll16(nb + kd1, kp1);
            gll16(nb + vd0, vp0); gll16(nb + vd1, vp1);
            kp0 += 128 * H_; kp1 += 128 * H_; vp0 += 128; vp1 += 128;
        }

        const char* Ks = KVs + cur * 32768;
        const char* Vs = Ks + 16384;
        const float* mrow = mptr + t * 128;

#pragma unroll
        for (int t4 = 0; t4 < 4; ++t4) {
            union { uint32_t u[4]; bf16x8 v; } pb0, pb1;
#pragma unroll
            for (int half = 0; half < 2; ++half) {
                const int c = 2 * t4 + half;
                bf16x8 kf0 = *(const bf16x8*)(Ks + (c * 16 + rl) * 128 + ((rg * 16) ^ swz));
                bf16x8 kf1 = *(const bf16x8*)(Ks + (c * 16 + rl) * 128 + ((64 + rg * 16) ^ swz));
                f32x4 s0 = {0, 0, 0, 0}, s1 = {0, 0, 0, 0};
                s0 = __builtin_amdgcn_mfma_f32_16x16x32_bf16(kf0, qf[0][0], s0, 0, 0, 0);
                s0 = __builtin_amdgcn_mfma_f32_16x16x32_bf16(kf1, qf[0][1], s0, 0, 0, 0);
                s1 = __builtin_amdgcn_mfma_f32_16x16x32_bf16(kf0, qf[1][0], s1, 0, 0, 0);
                s1 = __builtin_amdgcn_mfma_f32_16x16x32_bf16(kf1, qf[1][1], s1, 0, 0, 0);

                f32x4 m4 = *(const f32x4*)(mrow + 32 * t4 + 4 * half);
                float p0 = fast_exp2(fmaf(s0[0], SC, m4[0]));
                float p1 = fast_exp2(fmaf(s0[1], SC, m4[1]));
                float p2 = fast_exp2(fmaf(s0[2], SC, m4[2]));
                float p3 = fast_exp2(fmaf(s0[3], SC, m4[3]));
                float u0 = fast_exp2(fmaf(s1[0], SC, m4[0]));
                float u1 = fast_exp2(fmaf(s1[1], SC, m4[1]));
                float u2 = fast_exp2(fmaf(s1[2], SC, m4[2]));
                float u3 = fast_exp2(fmaf(s1[3], SC, m4[3]));
                pb0.u[half * 2]     = pack_bf16(p0, p1);
                pb0.u[half * 2 + 1] = pack_bf16(p2, p3);
                pb1.u[half * 2]     = pack_bf16(u0, u1);
                pb1.u[half * 2 + 1] = pack_bf16(u2, u3);
            }
            __builtin_amdgcn_s_setprio(1);
            lacc[0] = __builtin_amdgcn_mfma_f32_16x16x32_bf16(ones8, pb0.v, lacc[0], 0, 0, 0);
            lacc[1] = __builtin_amdgcn_mfma_f32_16x16x32_bf16(ones8, pb1.v, lacc[1], 0, 0, 0);
#pragma unroll
            for (int n = 0; n < 4; ++n) {
                bf16x8 af = *(const bf16x8*)(Vs + (n * 16 + rl) * 256 + ((t4 * 64 + rg * 16) ^ swz));
                cacc[0][n] = __builtin_amdgcn_mfma_f32_16x16x32_bf16(af, pb0.v, cacc[0][n], 0, 0, 0);
                cacc[1][n] = __builtin_amdgcn_mfma_f32_16x16x32_bf16(af, pb1.v, cacc[1][n], 0, 0, 0);
            }
            __builtin_amdgcn_s_setprio(0);
        }
        cur ^= 1;
    }

#pragma unroll
    for (int qm = 0; qm < 2; ++qm) {
        const float inv = 1.f / lacc[qm][0];
        const int row = qt0 + wv * 32 + qm * 16 + rl;
        __bf16* cb = ctx + (size_t)(b * S_ + row) * H_ + h * DH_;
#pragma unroll
        for (int n = 0; n < 4; ++n) {
            uint32_t u0 = pack_bf16(cacc[qm][n][0] * inv, cacc[qm][n][1] * inv);
            uint32_t u1 = pack_bf16(cacc[qm][n][2] * inv, cacc[qm][n][3] * inv);
            *(uint32_t*)(cb + n * 16 + rg * 4)     = u0;
            *(uint32_t*)(cb + n * 16 + rg * 4 + 2) = u1;
        }
    }
}

// ------------------------------------------------------------ layernorm ----
__global__ __launch_bounds__(256)
void ln_kernel(const __bf16* __restrict__ x, const float* __restrict__ gamma,
               const float* __restrict__ beta, float* __restrict__ out)
{
    const int row = blockIdx.x;
    const int t = threadIdx.x;
    const unsigned short* xr = (const unsigned short*)(x + (size_t)row * H_);
    ushort4 raw = *(const ushort4*)(xr + t * 4);
    union { uint32_t u; float f; } c0, c1, c2, c3;
    c0.u = (uint32_t)raw.x << 16; c1.u = (uint32_t)raw.y << 16;
    c2.u = (uint32_t)raw.z << 16; c3.u = (uint32_t)raw.w << 16;
    float v0 = c0.f, v1 = c1.f, v2 = c2.f, v3 = c3.f;
    float s  = v0 + v1 + v2 + v3;
    float ss = v0 * v0 + v1 * v1 + v2 * v2 + v3 * v3;
#pragma unroll
    for (int off = 1; off < 64; off <<= 1) {
        s  += __shfl_xor(s, off, 64);
        ss += __shfl_xor(ss, off, 64);
    }
    __shared__ float sb[8];
    const int wv = t >> 6, lane = t & 63;
    if (lane == 0) { sb[wv] = s; sb[4 + wv] = ss; }
    __syncthreads();
    s  = sb[0] + sb[1] + sb[2] + sb[3];
    ss = sb[4] + sb[5] + sb[6] + sb[7];
    const float mu = s * (1.f / H_);
    const float var = ss * (1.f / H_) - mu * mu;
    const float rstd = rsqrtf(var + 1e-12f);
    float4 g = *(const float4*)(gamma + t * 4);
    float4 bt = *(const float4*)(beta + t * 4);
    float4 o;
    o.x = (v0 - mu) * rstd * g.x + bt.x;
    o.y = (v1 - mu) * rstd * g.y + bt.y;
    o.z = (v2 - mu) * rstd * g.z + bt.z;
    o.w = (v3 - mu) * rstd * g.w + bt.w;
    *(float4*)(out + (size_t)row * H_ + t * 4) = o;
}

// -------------------------------------------------------------- launch ----
extern "C" void kernel_launch(void* const* d_in, const int* in_sizes, int n_in,
                              void* d_out, int out_size, void* d_ws, size_t ws_size,
                              hipStream_t stream)
{
    const float* hs    = (const float*)d_in[0];
    const float* mask  = (const float*)d_in[1];
    const float* Wq    = (const float*)d_in[2];
    const float* bq    = (const float*)d_in[3];
    const float* Wk    = (const float*)d_in[4];
    const float* bk    = (const float*)d_in[5];
    const float* Wv    = (const float*)d_in[6];
    const float* bv    = (const float*)d_in[7];
    const float* Wo    = (const float*)d_in[8];
    const float* bo    = (const float*)d_in[9];
    const float* gamma = (const float*)d_in[10];
    const float* beta  = (const float*)d_in[11];

    char* ws = (char*)d_ws;
    const size_t MB = 1ull << 20;
    __bf16* x_bf   = (__bf16*)(ws);             // 16 MB (dead after QKV GEMM)
    __bf16* wqkv   = (__bf16*)(ws + 16 * MB);   // 6 MB concat [Wq;Wk;Wv]
    __bf16* wo_bf  = (__bf16*)(ws + 22 * MB);   // 2 MB
    __bf16* q_bf   = (__bf16*)(ws + 24 * MB);   // 16 MB (later pre_bf)
    __bf16* k_bf   = (__bf16*)(ws + 40 * MB);   // 16 MB
    __bf16* vt_bf  = (__bf16*)(ws + 56 * MB);   // 16 MB
    float*  msk2   = (float*)(ws + 72 * MB);    // 32 KB pre-scaled mask
    float*  bqkv   = (float*)(ws + 72 * MB + (64 << 10));  // 12 KB concat bias
    __bf16* ctx_bf = (__bf16*)(ws);             // aliases x_bf (x dead by then)
    __bf16* pre_bf = (__bf16*)(ws + 24 * MB);   // 16 MB, aliases q (dead by then)

    prep_kernel<<<6160, 256, 0, stream>>>(hs, Wq, Wk, Wv, Wo, mask, bq, bk, bv,
                                          x_bf, wqkv, wo_bf, msk2, bqkv);

    // fused QKV projection, 256^2 8-wave pipelined tile
    gemm_qkv256<<<dim3(3 * H_ / 256, M_ / 256), 512, 0, stream>>>(
        x_bf, wqkv, bqkv, q_bf, k_bf, vt_bf);

    attn_fwd<<<dim3(S_ / 256 * NH_ * B_), 512, 0, stream>>>(q_bf, k_bf, vt_bf, msk2, ctx_bf);

    gemm_wo<<<dim3(H_ / 128, M_ / 128), 256, 0, stream>>>(
        ctx_bf, wo_bf, bo, hs, pre_bf);

    ln_kernel<<<M_, 256, 0, stream>>>(pre_bf, gamma, beta, (float*)d_out);
}

// Round 17
// 199.690 us; speedup vs baseline: 1.0332x; 1.0033x over previous
//
#include <hip/hip_runtime.h>
#include <hip/hip_bf16.h>
#include <stdint.h>

#define B_ 4
#define S_ 2048
#define H_ 1024
#define NH_ 16
#define DH_ 64
#define M_ (B_*S_)   // 8192

typedef __bf16 bf16x8 __attribute__((ext_vector_type(8)));
typedef float f32x4 __attribute__((ext_vector_type(4)));

static_assert(sizeof(__bf16) == 2, "bf16 size");

__device__ __forceinline__ uint32_t pack_bf16(float lo, float hi)
{
    union { __bf16 h[2]; uint32_t u; } t;
    t.h[0] = (__bf16)lo; t.h[1] = (__bf16)hi;
    return t.u;
}

__device__ __forceinline__ float fast_exp2(float x)
{
#if __has_builtin(__builtin_amdgcn_exp2f)
    return __builtin_amdgcn_exp2f(x);
#else
    return exp2f(x);
#endif
}

// async global->LDS, 16B per lane. LDS dest = wave-uniform base + lane*16.
__device__ __forceinline__ void gll16(void* lds, const void* g)
{
    __builtin_amdgcn_global_load_lds(
        (const __attribute__((address_space(1))) unsigned int*)g,
        (__attribute__((address_space(3))) unsigned int*)lds,
        16, 0, 0);
}

// ----------------------------------------------------------------- prep ----
__device__ __forceinline__ void cast8(const float* __restrict__ s, __bf16* __restrict__ d, int i)
{
    float4 a = *(const float4*)(s + i);
    float4 b = *(const float4*)(s + i + 4);
    bf16x8 o;
    o[0] = (__bf16)a.x; o[1] = (__bf16)a.y; o[2] = (__bf16)a.z; o[3] = (__bf16)a.w;
    o[4] = (__bf16)b.x; o[5] = (__bf16)b.y; o[6] = (__bf16)b.z; o[7] = (__bf16)b.w;
    *(bf16x8*)(d + i) = o;
}

__global__ __launch_bounds__(256)
void prep_kernel(const float* __restrict__ hs,
                 const float* __restrict__ Wq, const float* __restrict__ Wk,
                 const float* __restrict__ Wv, const float* __restrict__ Wo,
                 const float* __restrict__ mask,
                 const float* __restrict__ bq, const float* __restrict__ bk,
                 const float* __restrict__ bv,
                 __bf16* __restrict__ x_bf, __bf16* __restrict__ wqkv,
                 __bf16* __restrict__ wo_bf, float* __restrict__ msk2,
                 float* __restrict__ bqkv)
{
    const int bid = blockIdx.x, tid = threadIdx.x;
    const int nw = H_ * H_;
    if (bid < 4096) {
        cast8(hs, x_bf, bid * 2048 + tid * 8);
    } else if (bid < 4608) {
        cast8(Wq, wqkv, (bid - 4096) * 2048 + tid * 8);
    } else if (bid < 5120) {
        cast8(Wk, wqkv + nw, (bid - 4608) * 2048 + tid * 8);
    } else if (bid < 5632) {
        cast8(Wv, wqkv + 2 * nw, (bid - 5120) * 2048 + tid * 8);
    } else if (bid < 6144) {
        cast8(Wo, wo_bf, (bid - 5632) * 2048 + tid * 8);
    } else if (bid < 6148) {
        const int i = (bid - 6144) * 2048 + tid * 8;
        float4 a = *(const float4*)(mask + i);
        float4 c = *(const float4*)(mask + i + 4);
        const float L = 1.44269504089f;
        float4 sa = {a.x * L, a.y * L, a.z * L, a.w * L};
        float4 sc = {c.x * L, c.y * L, c.z * L, c.w * L};
        *(float4*)(msk2 + i)     = sa;
        *(float4*)(msk2 + i + 4) = sc;
    } else {
        const int j = (bid - 6148) * 256 + tid;
        const float* src = (j < H_) ? bq : (j < 2 * H_) ? bk : bv;
        bqkv[j] = src[j & (H_ - 1)];
    }
}

// -------------------------------------------------- Q/K GEMM (256^2 tile) ----
// C[M,2048] = x @ [Wq;Wk]^T + b. Grid 8x32 = 256 blocks = 1/CU EXACT.
// 256x256 tile, BK=32, 8 waves (2Mx4N, per-wave 128x64), 4-buffer LDS ring
// (128 KB), 2-deep prefetch, counted vmcnt(4), per-phase interleave + setprio.
__global__ __launch_bounds__(512, 2)
void gemm_qkv256(const __bf16* __restrict__ A, const __bf16* __restrict__ Bw,
                 const float* __restrict__ bias, __bf16* __restrict__ outq,
                 __bf16* __restrict__ outk)
{
    __shared__ __align__(16) char LDS[4 * 32768];   // ring: [A 16K | B 16K] x4

    const int tid  = threadIdx.x;
    const int lane = tid & 63, wv = tid >> 6;
    const int wr = wv >> 2, wc = wv & 3;           // 2x4 wave grid, 128x64 each
    const int m0 = blockIdx.y * 256, n0 = blockIdx.x * 256;
    const int rl = lane & 15, rg = lane >> 4;

    const int sRow = tid >> 2;
    const int sSw  = 8 * ((tid & 3) ^ ((tid >> 3) & 3));
    const int kboff = (rg ^ ((rl >> 1) & 3)) << 4;

    f32x4 acc[8][4] = {};

    auto stage = [&](int buf, int t) {
        char* base = LDS + buf * 32768;
        const int k0 = t * 32;
#pragma unroll
        for (int r = 0; r < 2; ++r) {
            gll16(base + r * 8192 + wv * 1024,
                  A  + (size_t)(m0 + r * 128 + sRow) * H_ + k0 + sSw);
            gll16(base + 16384 + r * 8192 + wv * 1024,
                  Bw + (size_t)(n0 + r * 128 + sRow) * H_ + k0 + sSw);
        }
    };

    stage(0, 0);
    stage(1, 1);
    const int NTK = H_ / 32;
    for (int t = 0; t < NTK; ++t) {
        if (t + 1 < NTK)
            asm volatile("s_waitcnt vmcnt(4)" ::: "memory");
        else
            asm volatile("s_waitcnt vmcnt(0)" ::: "memory");
        __builtin_amdgcn_s_barrier();
        __builtin_amdgcn_sched_barrier(0);

        const char* As = LDS + (t & 3) * 32768;
        const char* Bs = As + 16384;
        const bool pf = (t + 2) < NTK;
        char* nb = LDS + ((t + 2) & 3) * 32768;
        const int nk0 = (t + 2) * 32;

        bf16x8 bfr[4];
#pragma unroll
        for (int n = 0; n < 4; ++n)
            bfr[n] = *(const bf16x8*)(Bs + (wc * 64 + n * 16 + rl) * 64 + kboff);

#pragma unroll
        for (int ph = 0; ph < 2; ++ph) {
            bf16x8 af[4];
#pragma unroll
            for (int i = 0; i < 4; ++i)
                af[i] = *(const bf16x8*)(As + (wr * 128 + (ph * 4 + i) * 16 + rl) * 64 + kboff);
            if (pf) {
                gll16(nb + (ph ? 16384 : 0) + wv * 1024,
                      (ph ? Bw : A) + (size_t)((ph ? n0 : m0) + sRow) * H_ + nk0 + sSw);
                gll16(nb + (ph ? 16384 : 0) + 8192 + wv * 1024,
                      (ph ? Bw : A) + (size_t)((ph ? n0 : m0) + 128 + sRow) * H_ + nk0 + sSw);
            }
            __builtin_amdgcn_s_barrier();
            asm volatile("s_waitcnt lgkmcnt(0)" ::: "memory");
            __builtin_amdgcn_sched_barrier(0);
            __builtin_amdgcn_s_setprio(1);
#pragma unroll
            for (int i = 0; i < 4; ++i)
#pragma unroll
                for (int n = 0; n < 4; ++n)
                    acc[ph * 4 + i][n] = __builtin_amdgcn_mfma_f32_16x16x32_bf16(
                        af[i], bfr[n], acc[ph * 4 + i][n], 0, 0, 0);
            __builtin_amdgcn_s_setprio(0);
        }
    }

    const int seg = n0 >> 10;                      // block-uniform: 0=Q, 1=K
    __bf16* o = (seg == 0) ? outq : outk;
#pragma unroll
    for (int m = 0; m < 8; ++m)
#pragma unroll
        for (int n = 0; n < 4; ++n) {
            const int col = n0 + wc * 64 + n * 16 + rl;
            const float bv = bias[col];
            const int cs = col & 1023;
            const int row0 = m0 + wr * 128 + m * 16 + rg * 4;
#pragma unroll
            for (int r = 0; r < 4; ++r)
                o[(size_t)(row0 + r) * H_ + cs] = (__bf16)(acc[m][n][r] + bv);
        }
}

// --------------------------------------------------- V GEMM (128^2 tile) ----
// vt[B,NH,DH,S] = (x @ Wv^T + bv)^T. Grid 8x64 = 512 blocks = 2/CU EXACT,
// 2-resident (64 KB). BK=32 4-buffer ring, counted vmcnt. V^T epilogue via
// XOR-swizzled LDS transpose + coalesced 16B stores.
__global__ __launch_bounds__(256)
void gemm_v128(const __bf16* __restrict__ A, const __bf16* __restrict__ Bw,
               const float* __restrict__ bias, __bf16* __restrict__ outvt)
{
    __shared__ __align__(16) char LDS[4 * 16384];   // ring: [A 8K | B 8K] x4

    const int tid  = threadIdx.x;
    const int lane = tid & 63, wv = tid >> 6;
    const int wr = wv >> 1, wc = wv & 1;
    const int m0 = blockIdx.y * 128, n0 = blockIdx.x * 128;
    const int rl = lane & 15, rg = lane >> 4;

    const int sRow = wv * 16 + (lane >> 2);
    const int sSw  = 8 * ((lane & 3) ^ ((lane >> 3) & 3));
    const int kboff = (rg ^ ((rl >> 1) & 3)) << 4;

    f32x4 acc[4][4] = {};

    auto stage = [&](int buf, int k0) {
        char* As = LDS + buf * 16384;
#pragma unroll
        for (int p = 0; p < 2; ++p) {
            gll16(As + p * 4096 + wv * 1024,
                  A  + (size_t)(m0 + p * 64 + sRow) * H_ + k0 + sSw);
            gll16(As + 8192 + p * 4096 + wv * 1024,
                  Bw + (size_t)(n0 + p * 64 + sRow) * H_ + k0 + sSw);
        }
    };

    stage(0, 0);
    stage(1, 32);
    const int NTK = H_ / 32;
    for (int t = 0; t < NTK; ++t) {
        if (t + 1 < NTK)
            asm volatile("s_waitcnt vmcnt(4) lgkmcnt(0)" ::: "memory");
        else
            asm volatile("s_waitcnt vmcnt(0) lgkmcnt(0)" ::: "memory");
        __builtin_amdgcn_s_barrier();
        __builtin_amdgcn_sched_barrier(0);
        if (t + 2 < NTK) stage((t + 2) & 3, (t + 2) * 32);

        const char* As = LDS + (t & 3) * 16384;
        const char* Bs = As + 8192;
        bf16x8 af[4], bfr[4];
#pragma unroll
        for (int n = 0; n < 4; ++n)
            bfr[n] = *(const bf16x8*)(Bs + (wc * 64 + n * 16 + rl) * 64 + kboff);
#pragma unroll
        for (int m = 0; m < 4; ++m)
            af[m] = *(const bf16x8*)(As + (wr * 64 + m * 16 + rl) * 64 + kboff);
#pragma unroll
        for (int m = 0; m < 4; ++m)
#pragma unroll
            for (int n = 0; n < 4; ++n)
                acc[m][n] = __builtin_amdgcn_mfma_f32_16x16x32_bf16(af[m], bfr[n], acc[m][n], 0, 0, 0);
    }
    __syncthreads();                                // LDS reusable by epilogue

    // V^T: transpose the 128x128 tile in LDS (XOR (lcol&15)<<4), then
    // coalesced 16B stores (row = d, contiguous in s).
#pragma unroll
    for (int m = 0; m < 4; ++m)
#pragma unroll
        for (int n = 0; n < 4; ++n) {
            const int lcol = wc * 64 + n * 16 + rl;      // local d
            const int ls0  = wr * 64 + m * 16 + rg * 4;  // local s
            const float bv = bias[n0 + lcol];
            uint32_t w0 = pack_bf16(acc[m][n][0] + bv, acc[m][n][1] + bv);
            uint32_t w1 = pack_bf16(acc[m][n][2] + bv, acc[m][n][3] + bv);
            const int xorv = (lcol & 15) << 4;
            *(uint32_t*)(LDS + lcol * 256 + ((ls0 * 2) ^ xorv))       = w0;
            *(uint32_t*)(LDS + lcol * 256 + (((ls0 + 2) * 2) ^ xorv)) = w1;
        }
    __syncthreads();
    const int bb = m0 >> 11, s0g = m0 & (S_ - 1);
#pragma unroll
    for (int pass = 0; pass < 4; ++pass) {
        const int dd = pass * 32 + wv * 8 + (lane >> 3);
        const int ch = (lane & 7) * 16;                  // byte chunk in row
        const int cs = n0 + dd;                          // V col 0..1023
        const int hh = cs >> 6, dv = cs & 63;
        __bf16* dst = outvt + ((size_t)(bb * NH_ + hh) * DH_ + dv) * S_ + s0g;
#pragma unroll
        for (int c = 0; c < 2; ++c) {
            bf16x8 vvv = *(const bf16x8*)(LDS + dd * 256 + ((ch + c * 128) ^ ((dd & 15) << 4)));
            *(bf16x8*)(dst + (ch >> 1) + c * 64) = vvv;
        }
    }
}

// ----------------------------------------------------- Wo GEMM (128^2) ----
__global__ __launch_bounds__(256)
void gemm_wo(const __bf16* __restrict__ A, const __bf16* __restrict__ Bw,
             const float* __restrict__ bias, const float* __restrict__ resid,
             __bf16* __restrict__ outp)
{
    __shared__ __align__(16) char LDS[4 * 16384];   // ring: [A 8K | B 8K] x4

    const int tid  = threadIdx.x;
    const int lane = tid & 63, wv = tid >> 6;
    const int wr = wv >> 1, wc = wv & 1;
    const int m0 = blockIdx.y * 128, n0 = blockIdx.x * 128;
    const int rl = lane & 15, rg = lane >> 4;

    const int sRow = wv * 16 + (lane >> 2);
    const int sSw  = 8 * ((lane & 3) ^ ((lane >> 3) & 3));
    const int kboff = (rg ^ ((rl >> 1) & 3)) << 4;

    f32x4 acc[4][4] = {};

    auto stage = [&](int buf, int k0) {
        char* As = LDS + buf * 16384;
#pragma unroll
        for (int p = 0; p < 2; ++p) {
            gll16(As + p * 4096 + wv * 1024,
                  A  + (size_t)(m0 + p * 64 + sRow) * H_ + k0 + sSw);
            gll16(As + 8192 + p * 4096 + wv * 1024,
                  Bw + (size_t)(n0 + p * 64 + sRow) * H_ + k0 + sSw);
        }
    };

    stage(0, 0);
    stage(1, 32);
    const int NTK = H_ / 32;
    for (int t = 0; t < NTK; ++t) {
        if (t + 1 < NTK)
            asm volatile("s_waitcnt vmcnt(4) lgkmcnt(0)" ::: "memory");
        else
            asm volatile("s_waitcnt vmcnt(0) lgkmcnt(0)" ::: "memory");
        __builtin_amdgcn_s_barrier();
        __builtin_amdgcn_sched_barrier(0);
        if (t + 2 < NTK) stage((t + 2) & 3, (t + 2) * 32);

        const char* As = LDS + (t & 3) * 16384;
        const char* Bs = As + 8192;
        bf16x8 af[4], bfr[4];
#pragma unroll
        for (int n = 0; n < 4; ++n)
            bfr[n] = *(const bf16x8*)(Bs + (wc * 64 + n * 16 + rl) * 64 + kboff);
#pragma unroll
        for (int m = 0; m < 4; ++m)
            af[m] = *(const bf16x8*)(As + (wr * 64 + m * 16 + rl) * 64 + kboff);
#pragma unroll
        for (int m = 0; m < 4; ++m)
#pragma unroll
            for (int n = 0; n < 4; ++n)
                acc[m][n] = __builtin_amdgcn_mfma_f32_16x16x32_bf16(af[m], bfr[n], acc[m][n], 0, 0, 0);
    }

#pragma unroll
    for (int m = 0; m < 4; ++m)
#pragma unroll
        for (int n = 0; n < 4; ++n) {
            const int col = n0 + wc * 64 + n * 16 + rl;
            const float bv = bias[col];
            const int row0 = m0 + wr * 64 + m * 16 + rg * 4;
#pragma unroll
            for (int r = 0; r < 4; ++r) {
                const size_t idx = (size_t)(row0 + r) * H_ + col;
                outp[idx] = (__bf16)(acc[m][n][r] + bv + resid[idx]);
            }
        }
}

// ------------------------------------------------------------ attention ----
// R13 structure (best measured: 91.5 us). Swapped QK^T + permuted-K LDS ->
// lane-local x32 B-fragments for PV & lsum (zero cross-lane). Fixed-m
// softmax. 32 q-rows/wave, 8-wave blocks, KVBLK=128, 64 KB dbuf, single
// barrier/tile + counted waits, setprio around PV cluster, XCD swizzle.
__global__ __launch_bounds__(512)
void attn_fwd(const __bf16* __restrict__ q, const __bf16* __restrict__ k,
              const __bf16* __restrict__ vt, const float* __restrict__ msk2,
              __bf16* __restrict__ ctx)
{
    __shared__ __align__(16) char KVs[2 * 32768];   // 64 KB exactly

    const int phys = blockIdx.x;
    const int orig = (phys & 7) * 64 + (phys >> 3);
    const int qt0 = (orig & 7) * 256;
    const int hg = orig >> 3;
    const int h = hg & (NH_ - 1), b = hg >> 4;

    const int tid = threadIdx.x, lane = tid & 63, wv = tid >> 6;
    const int rl = lane & 15, rg = lane >> 4;
    const int swz = (rl & 7) << 4;
    const float SC = 0.125f * 1.44269504089f;
    const float* mptr = msk2 + (size_t)b * S_ + rg * 8;

    bf16x8 qf[2][2];
#pragma unroll
    for (int qm = 0; qm < 2; ++qm)
#pragma unroll
        for (int ks = 0; ks < 2; ++ks)
            qf[qm][ks] = *(const bf16x8*)(q + (size_t)(b * S_ + qt0 + wv * 32 + qm * 16 + rl) * H_
                                            + h * DH_ + ks * 32 + rg * 8);

    f32x4 cacc[2][4] = {};
    f32x4 lacc[2] = {};
    bf16x8 ones8;
#pragma unroll
    for (int i = 0; i < 8; ++i) ones8[i] = (__bf16)1.0f;

    const int kR = lane >> 3, kS = lane & 7;
    const int vR = lane >> 4, vS = lane & 15;
    const __bf16* kbase = k  + (size_t)b * S_ * H_ + h * DH_;
    const __bf16* vbase = vt + (size_t)(b * NH_ + h) * DH_ * S_;

    auto permk = [](int r) {
        return ((r >> 5) << 5) + 8 * ((r >> 2) & 3) + 4 * ((r >> 4) & 1) + (r & 3);
    };

    const int krow0 = wv * 8 + kR, krow1 = 64 + krow0;
    const int vrow0 = wv * 4 + vR, vrow1 = 32 + vrow0;
    const __bf16* kp0 = kbase + (size_t)permk(krow0) * H_ + 8 * (kS ^ (krow0 & 7));
    const __bf16* kp1 = kbase + (size_t)permk(krow1) * H_ + 8 * (kS ^ (krow1 & 7));
    const __bf16* vp0 = vbase + (size_t)vrow0 * S_ + 8 * (vS ^ (vrow0 & 7));
    const __bf16* vp1 = vbase + (size_t)vrow1 * S_ + 8 * (vS ^ (vrow1 & 7));
    const int kd0 = (wv * 8) * 128, kd1 = (64 + wv * 8) * 128;
    const int vd0 = 16384 + (wv * 4) * 256, vd1 = 16384 + (32 + wv * 4) * 256;

    gll16(KVs + kd0, kp0); gll16(KVs + kd1, kp1);
    gll16(KVs + vd0, vp0); gll16(KVs + vd1, vp1);
    kp0 += 128 * H_; kp1 += 128 * H_; vp0 += 128; vp1 += 128;

    const int NT = S_ / 128;
    int cur = 0;
    for (int t = 0; t < NT; ++t) {
        asm volatile("s_waitcnt vmcnt(0) lgkmcnt(0)" ::: "memory");
        __builtin_amdgcn_s_barrier();
        __builtin_amdgcn_sched_barrier(0);

        if (t + 1 < NT) {
            char* nb = KVs + (cur ^ 1) * 32768;
            gll16(nb + kd0, kp0); gll16(nb + kd1, kp1);
            gll16(nb + vd0, vp0); gll16(nb + vd1, vp1);
            kp0 += 128 * H_; kp1 += 128 * H_; vp0 += 128; vp1 += 128;
        }

        const char* Ks = KVs + cur * 32768;
        const char* Vs = Ks + 16384;
        const float* mrow = mptr + t * 128;

#pragma unroll
        for (int t4 = 0; t4 < 4; ++t4) {
            union { uint32_t u[4]; bf16x8 v; } pb0, pb1;
#pragma unroll
            for (int half = 0; half < 2; ++half) {
                const int c = 2 * t4 + half;
                bf16x8 kf0 = *(const bf16x8*)(Ks + (c * 16 + rl) * 128 + ((rg * 16) ^ swz));
                bf16x8 kf1 = *(const bf16x8*)(Ks + (c * 16 + rl) * 128 + ((64 + rg * 16) ^ swz));
                f32x4 s0 = {0, 0, 0, 0}, s1 = {0, 0, 0, 0};
                s0 = __builtin_amdgcn_mfma_f32_16x16x32_bf16(kf0, qf[0][0], s0, 0, 0, 0);
                s0 = __builtin_amdgcn_mfma_f32_16x16x32_bf16(kf1, qf[0][1], s0, 0, 0, 0);
                s1 = __builtin_amdgcn_mfma_f32_16x16x32_bf16(kf0, qf[1][0], s1, 0, 0, 0);
                s1 = __builtin_amdgcn_mfma_f32_16x16x32_bf16(kf1, qf[1][1], s1, 0, 0, 0);

                f32x4 m4 = *(const f32x4*)(mrow + 32 * t4 + 4 * half);
                float p0 = fast_exp2(fmaf(s0[0], SC, m4[0]));
                float p1 = fast_exp2(fmaf(s0[1], SC, m4[1]));
                float p2 = fast_exp2(fmaf(s0[2], SC, m4[2]));
                float p3 = fast_exp2(fmaf(s0[3], SC, m4[3]));
                float u0 = fast_exp2(fmaf(s1[0], SC, m4[0]));
                float u1 = fast_exp2(fmaf(s1[1], SC, m4[1]));
                float u2 = fast_exp2(fmaf(s1[2], SC, m4[2]));
                float u3 = fast_exp2(fmaf(s1[3], SC, m4[3]));
                pb0.u[half * 2]     = pack_bf16(p0, p1);
                pb0.u[half * 2 + 1] = pack_bf16(p2, p3);
                pb1.u[half * 2]     = pack_bf16(u0, u1);
                pb1.u[half * 2 + 1] = pack_bf16(u2, u3);
            }
            __builtin_amdgcn_s_setprio(1);
            lacc[0] = __builtin_amdgcn_mfma_f32_16x16x32_bf16(ones8, pb0.v, lacc[0], 0, 0, 0);
            lacc[1] = __builtin_amdgcn_mfma_f32_16x16x32_bf16(ones8, pb1.v, lacc[1], 0, 0, 0);
#pragma unroll
            for (int n = 0; n < 4; ++n) {
                bf16x8 af = *(const bf16x8*)(Vs + (n * 16 + rl) * 256 + ((t4 * 64 + rg * 16) ^ swz));
                cacc[0][n] = __builtin_amdgcn_mfma_f32_16x16x32_bf16(af, pb0.v, cacc[0][n], 0, 0, 0);
                cacc[1][n] = __builtin_amdgcn_mfma_f32_16x16x32_bf16(af, pb1.v, cacc[1][n], 0, 0, 0);
            }
            __builtin_amdgcn_s_setprio(0);
        }
        cur ^= 1;
    }

#pragma unroll
    for (int qm = 0; qm < 2; ++qm) {
        const float inv = 1.f / lacc[qm][0];
        const int row = qt0 + wv * 32 + qm * 16 + rl;
        __bf16* cb = ctx + (size_t)(b * S_ + row) * H_ + h * DH_;
#pragma unroll
        for (int n = 0; n < 4; ++n) {
            uint32_t u0 = pack_bf16(cacc[qm][n][0] * inv, cacc[qm][n][1] * inv);
            uint32_t u1 = pack_bf16(cacc[qm][n][2] * inv, cacc[qm][n][3] * inv);
            *(uint32_t*)(cb + n * 16 + rg * 4)     = u0;
            *(uint32_t*)(cb + n * 16 + rg * 4 + 2) = u1;
        }
    }
}

// ------------------------------------------------------------ layernorm ----
__global__ __launch_bounds__(256)
void ln_kernel(const __bf16* __restrict__ x, const float* __restrict__ gamma,
               const float* __restrict__ beta, float* __restrict__ out)
{
    const int row = blockIdx.x;
    const int t = threadIdx.x;
    const unsigned short* xr = (const unsigned short*)(x + (size_t)row * H_);
    ushort4 raw = *(const ushort4*)(xr + t * 4);
    union { uint32_t u; float f; } c0, c1, c2, c3;
    c0.u = (uint32_t)raw.x << 16; c1.u = (uint32_t)raw.y << 16;
    c2.u = (uint32_t)raw.z << 16; c3.u = (uint32_t)raw.w << 16;
    float v0 = c0.f, v1 = c1.f, v2 = c2.f, v3 = c3.f;
    float s  = v0 + v1 + v2 + v3;
    float ss = v0 * v0 + v1 * v1 + v2 * v2 + v3 * v3;
#pragma unroll
    for (int off = 1; off < 64; off <<= 1) {
        s  += __shfl_xor(s, off, 64);
        ss += __shfl_xor(ss, off, 64);
    }
    __shared__ float sb[8];
    const int wv = t >> 6, lane = t & 63;
    if (lane == 0) { sb[wv] = s; sb[4 + wv] = ss; }
    __syncthreads();
    s  = sb[0] + sb[1] + sb[2] + sb[3];
    ss = sb[4] + sb[5] + sb[6] + sb[7];
    const float mu = s * (1.f / H_);
    const float var = ss * (1.f / H_) - mu * mu;
    const float rstd = rsqrtf(var + 1e-12f);
    float4 g = *(const float4*)(gamma + t * 4);
    float4 bt = *(const float4*)(beta + t * 4);
    float4 o;
    o.x = (v0 - mu) * rstd * g.x + bt.x;
    o.y = (v1 - mu) * rstd * g.y + bt.y;
    o.z = (v2 - mu) * rstd * g.z + bt.z;
    o.w = (v3 - mu) * rstd * g.w + bt.w;
    *(float4*)(out + (size_t)row * H_ + t * 4) = o;
}

// -------------------------------------------------------------- launch ----
extern "C" void kernel_launch(void* const* d_in, const int* in_sizes, int n_in,
                              void* d_out, int out_size, void* d_ws, size_t ws_size,
                              hipStream_t stream)
{
    const float* hs    = (const float*)d_in[0];
    const float* mask  = (const float*)d_in[1];
    const float* Wq    = (const float*)d_in[2];
    const float* bq    = (const float*)d_in[3];
    const float* Wk    = (const float*)d_in[4];
    const float* bk    = (const float*)d_in[5];
    const float* Wv    = (const float*)d_in[6];
    const float* bv    = (const float*)d_in[7];
    const float* Wo    = (const float*)d_in[8];
    const float* bo    = (const float*)d_in[9];
    const float* gamma = (const float*)d_in[10];
    const float* beta  = (const float*)d_in[11];

    char* ws = (char*)d_ws;
    const size_t MB = 1ull << 20;
    __bf16* x_bf   = (__bf16*)(ws);             // 16 MB (dead after QKV GEMMs)
    __bf16* wqkv   = (__bf16*)(ws + 16 * MB);   // 6 MB concat [Wq;Wk;Wv]
    __bf16* wo_bf  = (__bf16*)(ws + 22 * MB);   // 2 MB
    __bf16* q_bf   = (__bf16*)(ws + 24 * MB);   // 16 MB (later pre_bf)
    __bf16* k_bf   = (__bf16*)(ws + 40 * MB);   // 16 MB
    __bf16* vt_bf  = (__bf16*)(ws + 56 * MB);   // 16 MB
    float*  msk2   = (float*)(ws + 72 * MB);    // 32 KB pre-scaled mask
    float*  bqkv   = (float*)(ws + 72 * MB + (64 << 10));  // 12 KB concat bias
    __bf16* ctx_bf = (__bf16*)(ws);             // aliases x_bf (x dead by then)
    __bf16* pre_bf = (__bf16*)(ws + 24 * MB);   // 16 MB, aliases q (dead by then)

    const int nw = H_ * H_;

    prep_kernel<<<6160, 256, 0, stream>>>(hs, Wq, Wk, Wv, Wo, mask, bq, bk, bv,
                                          x_bf, wqkv, wo_bf, msk2, bqkv);

    // Q+K projection: 256^2 tile, grid 256 = 1/CU exact
    gemm_qkv256<<<dim3(2 * H_ / 256, M_ / 256), 512, 0, stream>>>(
        x_bf, wqkv, bqkv, q_bf, k_bf);

    // V projection + transpose: 128^2 tile, grid 512 = 2/CU exact
    gemm_v128<<<dim3(H_ / 128, M_ / 128), 256, 0, stream>>>(
        x_bf, wqkv + 2 * nw, bqkv + 2 * H_, vt_bf);

    attn_fwd<<<dim3(S_ / 256 * NH_ * B_), 512, 0, stream>>>(q_bf, k_bf, vt_bf, msk2, ctx_bf);

    gemm_wo<<<dim3(H_ / 128, M_ / 128), 256, 0, stream>>>(
        ctx_bf, wo_bf, bo, hs, pre_bf);

    ln_kernel<<<M_, 256, 0, stream>>>(pre_bf, gamma, beta, (float*)d_out);
}